// Round 1
// baseline (1451.975 us; speedup 1.0000x reference)
//
#include <hip/hip_runtime.h>
#include <cstddef>

namespace {

constexpr int kN    = 10000;   // nodes
constexpr int kE    = 160000;  // edges
constexpr int kD    = 512;     // feature dim
constexpr int kNinv = 4000;
constexpr int kNunk = 3000;
constexpr int kND   = kN * kD;
constexpr float kNegSlope = 0.2f;
constexpr float kLnEps    = 1e-5f;

__device__ inline void atomicMaxF(float* addr, float v) {
  if (v >= 0.f) {
    atomicMax(reinterpret_cast<int*>(addr), __float_as_int(v));
  } else {
    atomicMin(reinterpret_cast<unsigned int*>(addr), __float_as_uint(v));
  }
}

// ---------------------------------------------------------------------------
// Tiled fp32 GEMM: C[M,N] = concat(A1,A2)[M,K] * B + bias
//   A halves each have row stride 512; if K<=512 only A1 is used.
//   TRANSB=false: B is [K,N] row-major (ldb=N).
//   TRANSB=true : B is [N,K] row-major (ldb=512), i.e. C = A * B^T.
// 64x64 tile, BK=16, 256 threads, 4x4 micro-tile per thread.
// ---------------------------------------------------------------------------
template <bool TRANSB>
__global__ __launch_bounds__(256) void gemm_f32(
    const float* __restrict__ A1, const float* __restrict__ A2,
    const float* __restrict__ B, const float* __restrict__ bias,
    float* __restrict__ C, int M, int N, int K, int ldc) {
  __shared__ float As[16][68];  // stride 68: float4-aligned, <=2-way bank alias
  __shared__ float Bs[16][68];
  const int tid = threadIdx.x;
  const int bm = blockIdx.x * 64;
  const int bn = blockIdx.y * 64;
  const int am  = tid >> 2;         // 0..63
  const int akg = (tid & 3) << 2;   // 0,4,8,12
  const int tm  = (tid >> 4) << 2;  // 0..60
  const int tn  = (tid & 15) << 2;  // 0..60
  float acc[4][4] = {};
  for (int k0 = 0; k0 < K; k0 += 16) {
    // ---- stage A tile (transposed into LDS)
    {
      float4 av = make_float4(0.f, 0.f, 0.f, 0.f);
      const int gm = bm + am;
      const int kk = k0 + akg;
      if (gm < M) {
        if (kk < 512) av = *reinterpret_cast<const float4*>(A1 + (size_t)gm * 512 + kk);
        else          av = *reinterpret_cast<const float4*>(A2 + (size_t)gm * 512 + (kk - 512));
      }
      As[akg + 0][am] = av.x; As[akg + 1][am] = av.y;
      As[akg + 2][am] = av.z; As[akg + 3][am] = av.w;
    }
    // ---- stage B tile
    if (!TRANSB) {
      const int bk  = tid >> 4;
      const int bng = (tid & 15) << 2;
      const float4 bv = *reinterpret_cast<const float4*>(B + (size_t)(k0 + bk) * N + bn + bng);
      *reinterpret_cast<float4*>(&Bs[bk][bng]) = bv;
    } else {
      const int bnn = tid >> 2;
      const int bkg = (tid & 3) << 2;
      float4 bv = make_float4(0.f, 0.f, 0.f, 0.f);
      if (bn + bnn < N) bv = *reinterpret_cast<const float4*>(B + (size_t)(bn + bnn) * 512 + k0 + bkg);
      Bs[bkg + 0][bnn] = bv.x; Bs[bkg + 1][bnn] = bv.y;
      Bs[bkg + 2][bnn] = bv.z; Bs[bkg + 3][bnn] = bv.w;
    }
    __syncthreads();
#pragma unroll
    for (int k = 0; k < 16; ++k) {
      const float4 a = *reinterpret_cast<const float4*>(&As[k][tm]);
      const float4 b = *reinterpret_cast<const float4*>(&Bs[k][tn]);
      acc[0][0] += a.x * b.x; acc[0][1] += a.x * b.y; acc[0][2] += a.x * b.z; acc[0][3] += a.x * b.w;
      acc[1][0] += a.y * b.x; acc[1][1] += a.y * b.y; acc[1][2] += a.y * b.z; acc[1][3] += a.y * b.w;
      acc[2][0] += a.z * b.x; acc[2][1] += a.z * b.y; acc[2][2] += a.z * b.z; acc[2][3] += a.z * b.w;
      acc[3][0] += a.w * b.x; acc[3][1] += a.w * b.y; acc[3][2] += a.w * b.z; acc[3][3] += a.w * b.w;
    }
    __syncthreads();
  }
#pragma unroll
  for (int j = 0; j < 4; ++j) {
    const int gn = bn + tn + j;
    float bb = 0.f;
    if (bias != nullptr && gn < N) bb = bias[gn];
#pragma unroll
    for (int i = 0; i < 4; ++i) {
      const int gm = bm + tm + i;
      if (gm < M && gn < N) C[(size_t)gm * ldc + gn] = acc[i][j] + bb;
    }
  }
}

// ---------------------------------------------------------------------------
// Per-edge attention logits: s[e] = att . leaky_relu(xl[src] + xr[dst] + ea@We)
// One wave per edge; also atomic per-dst max.
// ---------------------------------------------------------------------------
__global__ __launch_bounds__(256) void edge_logits_kernel(
    const float* __restrict__ xl, const float* __restrict__ xr,
    const float* __restrict__ ea, const int* __restrict__ src,
    const int* __restrict__ dst, const float* __restrict__ We,
    const float* __restrict__ att, float* __restrict__ s,
    float* __restrict__ smax) {
  const int wid  = threadIdx.x >> 6;
  const int lane = threadIdx.x & 63;
  const int e = blockIdx.x * 4 + wid;
  if (e >= kE) return;
  const int sv = src[e];
  const int dv = dst[e];
  const float ea0 = ea[(size_t)e * 2 + 0];
  const float ea1 = ea[(size_t)e * 2 + 1];
  const float4* pl = reinterpret_cast<const float4*>(xl + (size_t)sv * kD);
  const float4* pr = reinterpret_cast<const float4*>(xr + (size_t)dv * kD);
  const float4* w0 = reinterpret_cast<const float4*>(We);
  const float4* w1 = reinterpret_cast<const float4*>(We + kD);
  const float4* pa = reinterpret_cast<const float4*>(att);
  float sum = 0.f;
#pragma unroll
  for (int r = 0; r < 2; ++r) {
    const int i = lane + r * 64;  // 128 float4 = 512 floats
    const float4 l4 = pl[i], r4 = pr[i], a4 = pa[i];
    const float4 v0 = w0[i], v1 = w1[i];
    float m;
    m = l4.x + r4.x + ea0 * v0.x + ea1 * v1.x; sum += a4.x * (m >= 0.f ? m : kNegSlope * m);
    m = l4.y + r4.y + ea0 * v0.y + ea1 * v1.y; sum += a4.y * (m >= 0.f ? m : kNegSlope * m);
    m = l4.z + r4.z + ea0 * v0.z + ea1 * v1.z; sum += a4.z * (m >= 0.f ? m : kNegSlope * m);
    m = l4.w + r4.w + ea0 * v0.w + ea1 * v1.w; sum += a4.w * (m >= 0.f ? m : kNegSlope * m);
  }
#pragma unroll
  for (int off = 32; off > 0; off >>= 1) sum += __shfl_xor(sum, off);
  if (lane == 0) {
    s[e] = sum;
    atomicMaxF(&smax[dv], sum);
  }
}

__global__ __launch_bounds__(256) void edge_exp_kernel(
    const float* __restrict__ s, const float* __restrict__ smax,
    const int* __restrict__ dst, float* __restrict__ aexp,
    float* __restrict__ denom) {
  const int e = blockIdx.x * 256 + threadIdx.x;
  if (e >= kE) return;
  const int dv = dst[e];
  const float v = expf(s[e] - smax[dv]);
  aexp[e] = v;
  atomicAdd(&denom[dv], v);
}

// One block per dst node: out[n] = sum_e alpha_e * xl[src_e]  + bias
__global__ __launch_bounds__(256) void aggregate_kernel(
    const float* __restrict__ xl, const float* __restrict__ aexp,
    const float* __restrict__ denom, const int* __restrict__ offs,
    const int* __restrict__ sorted, const int* __restrict__ src,
    const float* __restrict__ bias, float* __restrict__ hc) {
  const int n = blockIdx.x;
  const int tid = threadIdx.x;
  const int beg = offs[n];
  const int end = offs[n + 1];
  const float dn = denom[n];
  const float inv = 1.f / (dn > 0.f ? dn : 1.f);
  const int d = tid * 2;
  float a0 = 0.f, a1 = 0.f;
  for (int i = beg; i < end; ++i) {
    const int e = sorted[i];
    const float alpha = aexp[e] * inv;
    const float2 v = *reinterpret_cast<const float2*>(xl + (size_t)src[e] * kD + d);
    a0 += alpha * v.x;
    a1 += alpha * v.y;
  }
  const float2 b2 = *reinterpret_cast<const float2*>(bias + d);
  float2 o; o.x = a0 + b2.x; o.y = a1 + b2.y;
  *reinterpret_cast<float2*>(hc + (size_t)n * kD + d) = o;
}

// h = relu(layernorm(hc + h) * g + b), one block (256 thr) per row
__global__ __launch_bounds__(256) void add_ln_relu_kernel(
    float* __restrict__ h, const float* __restrict__ hc,
    const float* __restrict__ g, const float* __restrict__ b) {
  const int row = blockIdx.x;
  const int tid = threadIdx.x;
  const int d = tid * 2;
  const float2 hv = *reinterpret_cast<const float2*>(h + (size_t)row * kD + d);
  const float2 cv = *reinterpret_cast<const float2*>(hc + (size_t)row * kD + d);
  const float x0 = hv.x + cv.x;
  const float x1 = hv.y + cv.y;
  float sum = x0 + x1;
  float sq = x0 * x0 + x1 * x1;
#pragma unroll
  for (int off = 32; off > 0; off >>= 1) {
    sum += __shfl_xor(sum, off);
    sq  += __shfl_xor(sq, off);
  }
  __shared__ float ws[4], wq[4];
  const int wid = tid >> 6, lane = tid & 63;
  if (lane == 0) { ws[wid] = sum; wq[wid] = sq; }
  __syncthreads();
  sum = ws[0] + ws[1] + ws[2] + ws[3];
  sq  = wq[0] + wq[1] + wq[2] + wq[3];
  const float mean = sum * (1.f / kD);
  const float var  = sq * (1.f / kD) - mean * mean;
  const float rs = rsqrtf(var + kLnEps);
  float y0 = (x0 - mean) * rs * g[d]     + b[d];
  float y1 = (x1 - mean) * rs * g[d + 1] + b[d + 1];
  y0 = fmaxf(y0, 0.f);
  y1 = fmaxf(y1, 0.f);
  float2 o; o.x = y0; o.y = y1;
  *reinterpret_cast<float2*>(h + (size_t)row * kD + d) = o;
}

// ------------------------- CSR build helpers -------------------------------
__global__ void fill_f32(float* p, float v, int n) {
  const int i = blockIdx.x * 256 + threadIdx.x;
  if (i < n) p[i] = v;
}
__global__ void fill_i32(int* p, int v, int n) {
  const int i = blockIdx.x * 256 + threadIdx.x;
  if (i < n) p[i] = v;
}
__global__ void copy_i32(const int* a, int* b, int n) {
  const int i = blockIdx.x * 256 + threadIdx.x;
  if (i < n) b[i] = a[i];
}
__global__ void copy_f4(const float4* a, float4* b, int n4) {
  const int i = blockIdx.x * 256 + threadIdx.x;
  if (i < n4) b[i] = a[i];
}
__global__ void count_kernel(const int* __restrict__ dst, int* __restrict__ counts) {
  const int e = blockIdx.x * 256 + threadIdx.x;
  if (e < kE) atomicAdd(&counts[dst[e]], 1);
}
__global__ __launch_bounds__(1024) void scan_kernel(const int* __restrict__ counts,
                                                    int* __restrict__ offs, int n) {
  __shared__ int buf[1024];
  __shared__ int carry;
  const int tid = threadIdx.x;
  if (tid == 0) carry = 0;
  __syncthreads();
  for (int base = 0; base < n; base += 1024) {
    const int v = (base + tid < n) ? counts[base + tid] : 0;
    buf[tid] = v;
    __syncthreads();
    for (int off = 1; off < 1024; off <<= 1) {
      const int t = (tid >= off) ? buf[tid - off] : 0;
      __syncthreads();
      buf[tid] += t;
      __syncthreads();
    }
    if (base + tid < n) offs[base + tid] = carry + buf[tid] - v;
    __syncthreads();
    if (tid == 0) carry += buf[1023];
    __syncthreads();
  }
  if (tid == 0) offs[n] = carry;
}
__global__ void scatter_kernel(const int* __restrict__ dst, int* __restrict__ pos,
                               int* __restrict__ sorted) {
  const int e = blockIdx.x * 256 + threadIdx.x;
  if (e >= kE) return;
  const int p = atomicAdd(&pos[dst[e]], 1);
  sorted[p] = e;
}

}  // namespace

extern "C" void kernel_launch(void* const* d_in, const int* in_sizes, int n_in,
                              void* d_out, int out_size, void* d_ws, size_t ws_size,
                              hipStream_t stream) {
  const float* x         = (const float*)d_in[0];
  const float* edge_attr = (const float*)d_in[1];
  const float* emb_inv_W = (const float*)d_in[2];
  const float* emb_inv_b = (const float*)d_in[3];
  const float* emb_org_W = (const float*)d_in[4];
  const float* emb_org_b = (const float*)d_in[5];
  const float* gat_Wl    = (const float*)d_in[6];
  const float* gat_bl    = (const float*)d_in[7];
  const float* gat_Wr    = (const float*)d_in[8];
  const float* gat_br    = (const float*)d_in[9];
  const float* gat_We    = (const float*)d_in[10];
  const float* gat_att   = (const float*)d_in[11];
  const float* gat_bias  = (const float*)d_in[12];
  const float* ln_g      = (const float*)d_in[13];
  const float* ln_b      = (const float*)d_in[14];
  const float* lin0_W    = (const float*)d_in[15];
  const float* lin0_b    = (const float*)d_in[16];
  const float* lin1_W    = (const float*)d_in[17];
  const float* lin1_b    = (const float*)d_in[18];
  const int*   edge_idx  = (const int*)d_in[19];
  const int* src = edge_idx;
  const int* dst = edge_idx + kE;
  float* out = (float*)d_out;

  // ---- workspace layout (floats then ints) ----
  float* ws = (float*)d_ws;
  float* h0    = ws;               // [N,D] initial embedding (x0|x1)
  float* h     = h0 + kND;         // [N,D] running features
  float* xl    = h + kND;          // [N,D]
  float* xr    = xl + kND;         // [N,D]
  float* hc    = xr + kND;         // [N,D]
  float* sbuf  = hc + kND;         // [E]
  float* aexp  = sbuf + kE;        // [E]
  float* smax  = aexp + kE;        // [N]
  float* denom = smax + kN;        // [N]
  float* y0    = denom + kN;       // [4000,512]
  float* y1    = y0 + kNinv * kD;  // [3000,512]
  int* counts  = (int*)(y1 + kNunk * kD);  // [N]
  int* offs    = counts + kN;              // [N+1]
  int* pos     = offs + kN + 1;            // [N]
  int* sorted  = pos + kN;                 // [E]

  const dim3 blk(256);

  // ---- 1. embeddings: h0 = [x[:4000]@Winv+b ; x[4000:]@Worg+b]; h = h0
  {
    dim3 g0((kNinv + 63) / 64, kD / 64);
    gemm_f32<false><<<g0, blk, 0, stream>>>(x, nullptr, emb_inv_W, emb_inv_b,
                                            h0, kNinv, kD, kD, kD);
    dim3 g1((kN - kNinv + 63) / 64, kD / 64);
    gemm_f32<false><<<g1, blk, 0, stream>>>(x + (size_t)kNinv * kD, nullptr, emb_org_W,
                                            emb_org_b, h0 + (size_t)kNinv * kD,
                                            kN - kNinv, kD, kD, kD);
    copy_f4<<<dim3((kND / 4 + 255) / 256), blk, 0, stream>>>(
        (const float4*)h0, (float4*)h, kND / 4);
  }

  // ---- 2. CSR over dst (reused by all 3 layers)
  {
    fill_i32<<<dim3((kN + 255) / 256), blk, 0, stream>>>(counts, 0, kN);
    count_kernel<<<dim3((kE + 255) / 256), blk, 0, stream>>>(dst, counts);
    scan_kernel<<<dim3(1), dim3(1024), 0, stream>>>(counts, offs, kN);
    copy_i32<<<dim3((kN + 255) / 256), blk, 0, stream>>>(offs, pos, kN);
    scatter_kernel<<<dim3((kE + 255) / 256), blk, 0, stream>>>(dst, pos, sorted);
  }

  // ---- 3. GAT layers
  for (int k = 0; k < 3; ++k) {
    const float* Wl = gat_Wl + (size_t)k * kD * kD;
    const float* bl = gat_bl + (size_t)k * kD;
    const float* Wr = gat_Wr + (size_t)k * kD * kD;
    const float* br = gat_br + (size_t)k * kD;
    const float* We = gat_We + (size_t)k * 2 * kD;
    const float* at = gat_att + (size_t)k * kD;
    const float* bi = gat_bias + (size_t)k * kD;
    const float* lg = ln_g + (size_t)k * kD;
    const float* lb = ln_b + (size_t)k * kD;

    dim3 gg((kN + 63) / 64, kD / 64);
    gemm_f32<false><<<gg, blk, 0, stream>>>(h, nullptr, Wl, bl, xl, kN, kD, kD, kD);
    gemm_f32<false><<<gg, blk, 0, stream>>>(h, nullptr, Wr, br, xr, kN, kD, kD, kD);

    fill_f32<<<dim3((kN + 255) / 256), blk, 0, stream>>>(smax, -INFINITY, kN);
    fill_f32<<<dim3((kN + 255) / 256), blk, 0, stream>>>(denom, 0.f, kN);

    edge_logits_kernel<<<dim3(kE / 4), blk, 0, stream>>>(xl, xr, edge_attr, src, dst,
                                                         We, at, sbuf, smax);
    edge_exp_kernel<<<dim3((kE + 255) / 256), blk, 0, stream>>>(sbuf, smax, dst, aexp,
                                                                denom);
    aggregate_kernel<<<dim3(kN), blk, 0, stream>>>(xl, aexp, denom, offs, sorted, src,
                                                   bi, hc);
    add_ln_relu_kernel<<<dim3(kN), blk, 0, stream>>>(h, hc, lg, lb);
  }

  // ---- 4. heads: y0 = [x0 | h[:4000]] @ lin0_W + b ; y1 = [x1[-3000:] | h[-3000:]] @ lin1_W + b
  {
    dim3 g0((kNinv + 63) / 64, kD / 64);
    gemm_f32<false><<<g0, blk, 0, stream>>>(h0, h, lin0_W, lin0_b, y0,
                                            kNinv, kD, 2 * kD, kD);
    const size_t off = (size_t)(kN - kNunk) * kD;
    dim3 g1((kNunk + 63) / 64, kD / 64);
    gemm_f32<false><<<g1, blk, 0, stream>>>(h0 + off, h + off, lin1_W, lin1_b, y1,
                                            kNunk, kD, 2 * kD, kD);
  }

  // ---- 5. out = y0 @ y1^T  [4000,3000]
  {
    dim3 gf((kNinv + 63) / 64, (kNunk + 63) / 64);
    gemm_f32<true><<<gf, blk, 0, stream>>>(y0, nullptr, y1, nullptr, out,
                                           kNinv, kNunk, kD, kNunk);
  }
}

// Round 2
// 775.299 us; speedup vs baseline: 1.8728x; 1.8728x over previous
//
#include <hip/hip_runtime.h>
#include <cstddef>
#include <cstdint>

namespace {

using u16 = unsigned short;
typedef __attribute__((ext_vector_type(8))) unsigned short u16x8;
typedef __attribute__((ext_vector_type(8))) short bf16x8;
typedef __attribute__((ext_vector_type(4))) float f32x4;

constexpr int kN    = 10000;   // nodes
constexpr int kE    = 160000;  // edges
constexpr int kD    = 512;     // feature dim
constexpr int kNinv = 4000;
constexpr int kNunk = 3000;
constexpr int kND   = kN * kD;
constexpr float kNegSlope = 0.2f;
constexpr float kLnEps    = 1e-5f;

__device__ __forceinline__ float bf2f(u16 u) {
  return __uint_as_float((unsigned)u << 16);
}
__device__ __forceinline__ u16 f2bf(float f) {
  unsigned u = __float_as_uint(f);
  return (u16)((u + 0x7FFFu + ((u >> 16) & 1u)) >> 16);  // RNE
}

__device__ __forceinline__ void gload_lds16(const void* g, void* l) {
  __builtin_amdgcn_global_load_lds(
      (const __attribute__((address_space(1))) void*)(unsigned long long)(uintptr_t)g,
      (__attribute__((address_space(3))) void*)(unsigned)(uintptr_t)l,
      16, 0, 0);
}

__device__ inline void atomicMaxF(float* addr, float v) {
  if (v >= 0.f) {
    atomicMax(reinterpret_cast<int*>(addr), __float_as_int(v));
  } else {
    atomicMin(reinterpret_cast<unsigned int*>(addr), __float_as_uint(v));
  }
}

// ---------------------------------------------------------------------------
// bf16 MFMA GEMM: C[M,N] = A[M,K](bf16) * BT[N,K]^T(bf16) (+ bias)
// 128x128 tile, BK=64, 256 thr = 4 waves (2x2), 16x16x32 MFMA, 4x4 frags/wave.
// global_load_lds(16B) staging, XOR swizzle: LDS(row,slot) <- G(row,slot^(row&7))
// so the swizzled ds_read_b128 (slot^(r&7)) is 2-way-conflict (free, m136).
// Rows clamped to M-1 / N-1 when tile overhangs; writes guarded.
// ---------------------------------------------------------------------------
template <bool WRITE_F32, bool WRITE_BF16>
__global__ __launch_bounds__(256) void gemm_bf16(
    const u16* __restrict__ A, const u16* __restrict__ BT,
    const float* __restrict__ bias,
    float* __restrict__ Cf, u16* __restrict__ Cb,
    int M, int N, int K, int ldc) {
  __shared__ u16 As[128 * 64];  // 16 KB
  __shared__ u16 Bs[128 * 64];  // 16 KB
  const int tid  = threadIdx.x;
  const int lane = tid & 63;
  const int wid  = tid >> 6;
  const int bm = blockIdx.x * 128;
  const int bn = blockIdx.y * 128;
  const int wr = (wid >> 1) * 64;  // wave row offset in tile
  const int wc = (wid & 1) * 64;   // wave col offset in tile

  f32x4 acc[4][4];
#pragma unroll
  for (int m = 0; m < 4; ++m)
#pragma unroll
    for (int n = 0; n < 4; ++n) acc[m][n] = (f32x4){0.f, 0.f, 0.f, 0.f};

  const int srow = lane >> 3;          // 0..7 within instruction's 8 rows
  const int slot = lane & 7;           // 16B slot within 128B row

  for (int k0 = 0; k0 < K; k0 += 64) {
    // ---- stage A tile: 16KB = 16 x (1KB wave-instr); wave w does 4
#pragma unroll
    for (int t = 0; t < 4; ++t) {
      const int inst = wid * 4 + t;
      const int row  = inst * 8 + srow;              // 0..127
      const int scol = ((slot ^ (row & 7)) << 4);    // swizzled byte-in-row
      const int ar   = min(bm + row, M - 1);
      gload_lds16((const char*)A + ((size_t)ar * K + k0) * 2 + scol,
                  (char*)As + inst * 1024);
    }
    // ---- stage B tile (BT rows are output columns)
#pragma unroll
    for (int t = 0; t < 4; ++t) {
      const int inst = wid * 4 + t;
      const int row  = inst * 8 + srow;
      const int scol = ((slot ^ (row & 7)) << 4);
      const int bc   = min(bn + row, N - 1);
      gload_lds16((const char*)BT + ((size_t)bc * K + k0) * 2 + scol,
                  (char*)Bs + inst * 1024);
    }
    asm volatile("s_waitcnt vmcnt(0)" ::: "memory");
    __syncthreads();

#pragma unroll
    for (int kk = 0; kk < 2; ++kk) {  // two K=32 MFMA steps
      bf16x8 af[4], bfr[4];
#pragma unroll
      for (int m = 0; m < 4; ++m) {
        const int r = wr + m * 16 + (lane & 15);
        const int s = kk * 4 + (lane >> 4);
        af[m] = *(const bf16x8*)((const char*)As + r * 128 + ((s ^ (r & 7)) << 4));
      }
#pragma unroll
      for (int n = 0; n < 4; ++n) {
        const int c = wc + n * 16 + (lane & 15);
        const int s = kk * 4 + (lane >> 4);
        bfr[n] = *(const bf16x8*)((const char*)Bs + c * 128 + ((s ^ (c & 7)) << 4));
      }
#pragma unroll
      for (int m = 0; m < 4; ++m)
#pragma unroll
        for (int n = 0; n < 4; ++n)
          acc[m][n] = __builtin_amdgcn_mfma_f32_16x16x32_bf16(af[m], bfr[n],
                                                              acc[m][n], 0, 0, 0);
    }
    __syncthreads();
  }

  // ---- epilogue: C/D layout col=lane&15, row=(lane>>4)*4+j  [m89/m91]
#pragma unroll
  for (int m = 0; m < 4; ++m) {
    const int row0 = bm + wr + m * 16 + ((lane >> 4) << 2);
#pragma unroll
    for (int n = 0; n < 4; ++n) {
      const int col = bn + wc + n * 16 + (lane & 15);
      if (col < N) {
        const float bv = (bias != nullptr) ? bias[col] : 0.f;
#pragma unroll
        for (int j = 0; j < 4; ++j) {
          const int r = row0 + j;
          if (r < M) {
            const float v = acc[m][n][j] + bv;
            if (WRITE_F32) Cf[(size_t)r * ldc + col] = v;
            if (WRITE_BF16) Cb[(size_t)r * ldc + col] = f2bf(v);
          }
        }
      }
    }
  }
}

// ---------------------------------------------------------------------------
// WT[N,K] (bf16) = transpose(W[K,N] f32); 32x32 LDS tile
// ---------------------------------------------------------------------------
__global__ __launch_bounds__(256) void transpose_bf16(
    const float* __restrict__ W, u16* __restrict__ WT, int K, int N) {
  __shared__ float t[32][33];
  const int k0 = blockIdx.x * 32, n0 = blockIdx.y * 32;
  const int lx = threadIdx.x & 31, ly = threadIdx.x >> 5;  // 32 x 8
#pragma unroll
  for (int r = 0; r < 32; r += 8)
    t[ly + r][lx] = W[(size_t)(k0 + ly + r) * N + n0 + lx];
  __syncthreads();
#pragma unroll
  for (int r = 0; r < 32; r += 8)
    WT[(size_t)(n0 + ly + r) * K + k0 + lx] = f2bf(t[lx][ly + r]);
}

__global__ void convert_bf16_kernel(const float* __restrict__ in,
                                    u16* __restrict__ out, int n4) {
  const int i = blockIdx.x * 256 + threadIdx.x;
  if (i >= n4) return;
  const float4 v = reinterpret_cast<const float4*>(in)[i];
  u16 o[4] = {f2bf(v.x), f2bf(v.y), f2bf(v.z), f2bf(v.w)};
  *reinterpret_cast<ulonglong1*>(out + (size_t)i * 4) =
      *reinterpret_cast<ulonglong1*>(o);
}

// cat row: out[r][0:512] = a[r], out[r][512:1024] = b[r] (all bf16)
__global__ __launch_bounds__(256) void cat_rows_kernel(
    const u16* __restrict__ a, const u16* __restrict__ b,
    u16* __restrict__ out, int rows) {
  const int r = blockIdx.x;
  const int tid = threadIdx.x;
  const int off = tid * 4;
  const u16* srcp = (off < 512) ? (a + (size_t)r * 512 + off)
                                : (b + (size_t)r * 512 + off - 512);
  *reinterpret_cast<ushort4*>(out + (size_t)r * 1024 + off) =
      *reinterpret_cast<const ushort4*>(srcp);
}

// ---------------------------------------------------------------------------
// Per-edge attention logits (bf16 xl/xr): one wave per edge, lane owns 8 dims
// ---------------------------------------------------------------------------
__global__ __launch_bounds__(256) void edge_logits_kernel(
    const u16* __restrict__ xl, const u16* __restrict__ xr,
    const float* __restrict__ ea, const int* __restrict__ src,
    const int* __restrict__ dst, const float* __restrict__ We,
    const float* __restrict__ att, float* __restrict__ s,
    float* __restrict__ smax) {
  const int wid = threadIdx.x >> 6, lane = threadIdx.x & 63;
  const int e = blockIdx.x * 4 + wid;
  if (e >= kE) return;
  const int sv = src[e], dv = dst[e];
  const float ea0 = ea[(size_t)e * 2 + 0];
  const float ea1 = ea[(size_t)e * 2 + 1];
  const int d = lane * 8;
  const u16x8 l8 = *(const u16x8*)(xl + (size_t)sv * kD + d);
  const u16x8 r8 = *(const u16x8*)(xr + (size_t)dv * kD + d);
  float sum = 0.f;
#pragma unroll
  for (int i = 0; i < 8; ++i) {
    const float m = bf2f(l8[i]) + bf2f(r8[i]) + ea0 * We[d + i] + ea1 * We[kD + d + i];
    sum += att[d + i] * (m >= 0.f ? m : kNegSlope * m);
  }
#pragma unroll
  for (int off = 32; off > 0; off >>= 1) sum += __shfl_xor(sum, off);
  if (lane == 0) {
    s[e] = sum;
    atomicMaxF(&smax[dv], sum);
  }
}

__global__ __launch_bounds__(256) void edge_exp_kernel(
    const float* __restrict__ s, const float* __restrict__ smax,
    const int* __restrict__ dst, float* __restrict__ aexp,
    float* __restrict__ denom) {
  const int e = blockIdx.x * 256 + threadIdx.x;
  if (e >= kE) return;
  const int dv = dst[e];
  const float v = expf(s[e] - smax[dv]);
  aexp[e] = v;
  atomicAdd(&denom[dv], v);
}

// One block per dst node: hc[n] = sum_e alpha_e * xl[src_e] + bias
__global__ __launch_bounds__(256) void aggregate_kernel(
    const u16* __restrict__ xl, const float* __restrict__ aexp,
    const float* __restrict__ denom, const int* __restrict__ offs,
    const int* __restrict__ sorted, const int* __restrict__ src,
    const float* __restrict__ bias, float* __restrict__ hc) {
  const int n = blockIdx.x;
  const int tid = threadIdx.x;
  const int beg = offs[n], end = offs[n + 1];
  const float dn = denom[n];
  const float inv = 1.f / (dn > 0.f ? dn : 1.f);
  const int d = tid * 2;
  float a0 = 0.f, a1 = 0.f;
  for (int i = beg; i < end; ++i) {
    const int e = sorted[i];
    const float alpha = aexp[e] * inv;
    const unsigned v = *(const unsigned*)(xl + (size_t)src[e] * kD + d);
    a0 += alpha * __uint_as_float(v << 16);
    a1 += alpha * __uint_as_float(v & 0xffff0000u);
  }
  float2 o;
  o.x = a0 + bias[d];
  o.y = a1 + bias[d + 1];
  *reinterpret_cast<float2*>(hc + (size_t)n * kD + d) = o;
}

// h = relu(layernorm(hc + h) * g + b) in place; also writes bf16 copy
__global__ __launch_bounds__(256) void add_ln_relu_kernel(
    float* __restrict__ h, const float* __restrict__ hc,
    u16* __restrict__ hb, const float* __restrict__ g,
    const float* __restrict__ b) {
  const int row = blockIdx.x;
  const int tid = threadIdx.x;
  const int d = tid * 2;
  const float2 hv = *reinterpret_cast<const float2*>(h + (size_t)row * kD + d);
  const float2 cv = *reinterpret_cast<const float2*>(hc + (size_t)row * kD + d);
  const float x0 = hv.x + cv.x;
  const float x1 = hv.y + cv.y;
  float sum = x0 + x1;
  float sq = x0 * x0 + x1 * x1;
#pragma unroll
  for (int off = 32; off > 0; off >>= 1) {
    sum += __shfl_xor(sum, off);
    sq  += __shfl_xor(sq, off);
  }
  __shared__ float wsum[4], wsq[4];
  const int wid = tid >> 6, lane = tid & 63;
  if (lane == 0) { wsum[wid] = sum; wsq[wid] = sq; }
  __syncthreads();
  sum = wsum[0] + wsum[1] + wsum[2] + wsum[3];
  sq  = wsq[0] + wsq[1] + wsq[2] + wsq[3];
  const float mean = sum * (1.f / kD);
  const float var  = sq * (1.f / kD) - mean * mean;
  const float rs = rsqrtf(var + kLnEps);
  float y0 = (x0 - mean) * rs * g[d]     + b[d];
  float y1 = (x1 - mean) * rs * g[d + 1] + b[d + 1];
  y0 = fmaxf(y0, 0.f);
  y1 = fmaxf(y1, 0.f);
  float2 o; o.x = y0; o.y = y1;
  *reinterpret_cast<float2*>(h + (size_t)row * kD + d) = o;
  const unsigned packed = (unsigned)f2bf(y0) | ((unsigned)f2bf(y1) << 16);
  *reinterpret_cast<unsigned*>(hb + (size_t)row * kD + d) = packed;
}

// ------------------------- CSR build helpers -------------------------------
__global__ void fill_f32(float* p, float v, int n) {
  const int i = blockIdx.x * 256 + threadIdx.x;
  if (i < n) p[i] = v;
}
__global__ void fill_i32(int* p, int v, int n) {
  const int i = blockIdx.x * 256 + threadIdx.x;
  if (i < n) p[i] = v;
}
__global__ void copy_i32(const int* a, int* b, int n) {
  const int i = blockIdx.x * 256 + threadIdx.x;
  if (i < n) b[i] = a[i];
}
__global__ void count_kernel(const int* __restrict__ dst, int* __restrict__ counts) {
  const int e = blockIdx.x * 256 + threadIdx.x;
  if (e < kE) atomicAdd(&counts[dst[e]], 1);
}
__global__ __launch_bounds__(1024) void scan_kernel(const int* __restrict__ counts,
                                                    int* __restrict__ offs, int n) {
  __shared__ int buf[1024];
  __shared__ int carry;
  const int tid = threadIdx.x;
  if (tid == 0) carry = 0;
  __syncthreads();
  for (int base = 0; base < n; base += 1024) {
    const int v = (base + tid < n) ? counts[base + tid] : 0;
    buf[tid] = v;
    __syncthreads();
    for (int off = 1; off < 1024; off <<= 1) {
      const int t = (tid >= off) ? buf[tid - off] : 0;
      __syncthreads();
      buf[tid] += t;
      __syncthreads();
    }
    if (base + tid < n) offs[base + tid] = carry + buf[tid] - v;
    __syncthreads();
    if (tid == 0) carry += buf[1023];
    __syncthreads();
  }
  if (tid == 0) offs[n] = carry;
}
__global__ void scatter_kernel(const int* __restrict__ dst, int* __restrict__ pos,
                               int* __restrict__ sorted) {
  const int e = blockIdx.x * 256 + threadIdx.x;
  if (e >= kE) return;
  const int p = atomicAdd(&pos[dst[e]], 1);
  sorted[p] = e;
}

}  // namespace

extern "C" void kernel_launch(void* const* d_in, const int* in_sizes, int n_in,
                              void* d_out, int out_size, void* d_ws, size_t ws_size,
                              hipStream_t stream) {
  const float* x         = (const float*)d_in[0];
  const float* edge_attr = (const float*)d_in[1];
  const float* emb_inv_W = (const float*)d_in[2];
  const float* emb_inv_b = (const float*)d_in[3];
  const float* emb_org_W = (const float*)d_in[4];
  const float* emb_org_b = (const float*)d_in[5];
  const float* gat_Wl    = (const float*)d_in[6];
  const float* gat_bl    = (const float*)d_in[7];
  const float* gat_Wr    = (const float*)d_in[8];
  const float* gat_br    = (const float*)d_in[9];
  const float* gat_We    = (const float*)d_in[10];
  const float* gat_att   = (const float*)d_in[11];
  const float* gat_bias  = (const float*)d_in[12];
  const float* ln_g      = (const float*)d_in[13];
  const float* ln_b      = (const float*)d_in[14];
  const float* lin0_W    = (const float*)d_in[15];
  const float* lin0_b    = (const float*)d_in[16];
  const float* lin1_W    = (const float*)d_in[17];
  const float* lin1_b    = (const float*)d_in[18];
  const int*   edge_idx  = (const int*)d_in[19];
  const int* src = edge_idx;
  const int* dst = edge_idx + kE;
  float* out = (float*)d_out;

  // ---- workspace layout (~114 MB) ----
  float* hF    = (float*)d_ws;        // [N,D] residual stream (f32)
  float* hcF   = hF + kND;            // [N,D] GAT output (f32)
  float* sbuf  = hcF + kND;           // [E]
  float* aexp  = sbuf + kE;           // [E]
  float* smax  = aexp + kE;           // [N]
  float* denom = smax + kN;           // [N]
  u16* xb   = (u16*)(denom + kN);     // [N,D] bf16(x); later aliased by cat0
  u16* hb0  = xb + kND;               // [N,D] bf16 initial embedding
  u16* hb   = hb0 + kND;              // [N,D] bf16 running h
  u16* xlB  = hb + kND;               // [N,D] bf16
  u16* xrB  = xlB + kND;              // [N,D] bf16
  u16* cat1 = xrB + kND;              // [3000,1024]
  u16* y0b  = cat1 + kNunk * 1024;    // [4000,512]
  u16* y1b  = y0b + kNinv * 512;      // [3000,512]
  u16* wtp  = y1b + kNunk * 512;      // weight pool: 8*256K + 2*512K bf16
  u16* embInvT = wtp;
  u16* embOrgT = wtp + 262144;
  u16* WlT     = wtp + 2 * 262144;    // 3 x 262144
  u16* WrT     = wtp + 5 * 262144;
  u16* lin0T   = wtp + 8 * 262144;    // [512,1024]
  u16* lin1T   = lin0T + 524288;
  int* counts  = (int*)(lin1T + 524288);
  int* offs    = counts + kN;
  int* pos     = offs + kN + 1;
  int* sorted  = pos + kN;
  u16* cat0 = xb;  // alias: xb dead after embeddings; 4000*1024 <= kND

  const dim3 blk(256);
  auto cdiv = [](int a, int b) { return (a + b - 1) / b; };

  // ---- 0. weight transposes + x conversion (bf16)
  transpose_bf16<<<dim3(16, 16), blk, 0, stream>>>(emb_inv_W, embInvT, 512, 512);
  transpose_bf16<<<dim3(16, 16), blk, 0, stream>>>(emb_org_W, embOrgT, 512, 512);
  for (int k = 0; k < 3; ++k) {
    transpose_bf16<<<dim3(16, 16), blk, 0, stream>>>(gat_Wl + (size_t)k * kD * kD,
                                                     WlT + (size_t)k * 262144, 512, 512);
    transpose_bf16<<<dim3(16, 16), blk, 0, stream>>>(gat_Wr + (size_t)k * kD * kD,
                                                     WrT + (size_t)k * 262144, 512, 512);
  }
  transpose_bf16<<<dim3(32, 16), blk, 0, stream>>>(lin0_W, lin0T, 1024, 512);
  transpose_bf16<<<dim3(32, 16), blk, 0, stream>>>(lin1_W, lin1T, 1024, 512);
  convert_bf16_kernel<<<dim3(cdiv(kND / 4, 256)), blk, 0, stream>>>(x, xb, kND / 4);

  // ---- 1. embeddings -> hF (f32) + hb0 (bf16)
  gemm_bf16<true, true><<<dim3(cdiv(kNinv, 128), 4), blk, 0, stream>>>(
      xb, embInvT, emb_inv_b, hF, hb0, kNinv, kD, kD, kD);
  gemm_bf16<true, true><<<dim3(cdiv(kN - kNinv, 128), 4), blk, 0, stream>>>(
      xb + (size_t)kNinv * kD, embOrgT, emb_org_b, hF + (size_t)kNinv * kD,
      hb0 + (size_t)kNinv * kD, kN - kNinv, kD, kD, kD);

  // ---- 2. CSR over dst (reused by all 3 layers)
  fill_i32<<<dim3(cdiv(kN, 256)), blk, 0, stream>>>(counts, 0, kN);
  count_kernel<<<dim3(cdiv(kE, 256)), blk, 0, stream>>>(dst, counts);
  scan_kernel<<<dim3(1), dim3(1024), 0, stream>>>(counts, offs, kN);
  copy_i32<<<dim3(cdiv(kN, 256)), blk, 0, stream>>>(offs, pos, kN);
  scatter_kernel<<<dim3(cdiv(kE, 256)), blk, 0, stream>>>(dst, pos, sorted);

  // ---- 3. GAT layers
  for (int k = 0; k < 3; ++k) {
    const u16* hIn = (k == 0) ? hb0 : hb;
    const float* bl = gat_bl + (size_t)k * kD;
    const float* br = gat_br + (size_t)k * kD;
    const float* We = gat_We + (size_t)k * 2 * kD;
    const float* at = gat_att + (size_t)k * kD;
    const float* bi = gat_bias + (size_t)k * kD;
    const float* lg = ln_g + (size_t)k * kD;
    const float* lb = ln_b + (size_t)k * kD;

    gemm_bf16<false, true><<<dim3(cdiv(kN, 128), 4), blk, 0, stream>>>(
        hIn, WlT + (size_t)k * 262144, bl, nullptr, xlB, kN, kD, kD, kD);
    gemm_bf16<false, true><<<dim3(cdiv(kN, 128), 4), blk, 0, stream>>>(
        hIn, WrT + (size_t)k * 262144, br, nullptr, xrB, kN, kD, kD, kD);

    fill_f32<<<dim3(cdiv(kN, 256)), blk, 0, stream>>>(smax, -INFINITY, kN);
    fill_f32<<<dim3(cdiv(kN, 256)), blk, 0, stream>>>(denom, 0.f, kN);

    edge_logits_kernel<<<dim3(kE / 4), blk, 0, stream>>>(xlB, xrB, edge_attr, src,
                                                         dst, We, at, sbuf, smax);
    edge_exp_kernel<<<dim3(cdiv(kE, 256)), blk, 0, stream>>>(sbuf, smax, dst, aexp,
                                                             denom);
    aggregate_kernel<<<dim3(kN), blk, 0, stream>>>(xlB, aexp, denom, offs, sorted,
                                                   src, bi, hcF);
    add_ln_relu_kernel<<<dim3(kN), blk, 0, stream>>>(hF, hcF, hb, lg, lb);
  }

  // ---- 4. heads (bf16 out): y0 = [hb0 | hb][:4000] @ lin0, y1 = last 3000 @ lin1
  cat_rows_kernel<<<dim3(kNinv), blk, 0, stream>>>(hb0, hb, cat0, kNinv);
  cat_rows_kernel<<<dim3(kNunk), blk, 0, stream>>>(hb0 + (size_t)(kN - kNunk) * kD,
                                                   hb + (size_t)(kN - kNunk) * kD,
                                                   cat1, kNunk);
  gemm_bf16<false, true><<<dim3(cdiv(kNinv, 128), 4), blk, 0, stream>>>(
      cat0, lin0T, lin0_b, nullptr, y0b, kNinv, kD, 2 * kD, kD);
  gemm_bf16<false, true><<<dim3(cdiv(kNunk, 128), 4), blk, 0, stream>>>(
      cat1, lin1T, lin1_b, nullptr, y1b, kNunk, kD, 2 * kD, kD);

  // ---- 5. out = y0 @ y1^T  [4000,3000] (y1b is already the B^T layout)
  gemm_bf16<true, false><<<dim3(cdiv(kNinv, 128), cdiv(kNunk, 128)), blk, 0, stream>>>(
      y0b, y1b, nullptr, out, nullptr, kNinv, kNunk, kD, kNunk);
}

// Round 3
// 474.340 us; speedup vs baseline: 3.0610x; 1.6345x over previous
//
#include <hip/hip_runtime.h>
#include <cstddef>
#include <cstdint>

namespace {

using u16 = unsigned short;
typedef __attribute__((ext_vector_type(8))) unsigned short u16x8;
typedef __attribute__((ext_vector_type(8))) short bf16x8;
typedef __attribute__((ext_vector_type(4))) float f32x4;

constexpr int kN    = 10000;   // nodes
constexpr int kE    = 160000;  // edges
constexpr int kD    = 512;     // feature dim
constexpr int kNinv = 4000;
constexpr int kNunk = 3000;
constexpr int kND   = kN * kD;
constexpr int kChunk = 32;     // fused-attn LDS row capacity (online softmax chunk)
constexpr float kNegSlope = 0.2f;
constexpr float kLnEps    = 1e-5f;

__device__ __forceinline__ float bf2f(u16 u) {
  return __uint_as_float((unsigned)u << 16);
}
__device__ __forceinline__ u16 f2bf(float f) {
  unsigned u = __float_as_uint(f);
  return (u16)((u + 0x7FFFu + ((u >> 16) & 1u)) >> 16);  // RNE
}

__device__ __forceinline__ void gload_lds16(const void* g, void* l) {
  __builtin_amdgcn_global_load_lds(
      (const __attribute__((address_space(1))) void*)(unsigned long long)(uintptr_t)g,
      (__attribute__((address_space(3))) void*)(unsigned)(uintptr_t)l,
      16, 0, 0);
}

// ---------------------------------------------------------------------------
// bf16 MFMA GEMM: C[M,N] = A[M,K](bf16) * BT[N,K]^T(bf16) (+ bias)
//   A = [A1 | A2] split along K at 512 when A2 != nullptr (row stride 512 each);
//   else A1 row stride K.
//   Cb2/nsplit: bf16 cols >= nsplit go to Cb2 (col-nsplit), both ldc wide.
// 128x128 tile, BK=64, 256 thr = 4 waves (2x2), 16x16x32 MFMA.
// global_load_lds(16B), XOR swizzle (both-sides: pre-swizzled source + swizzled
// ds_read) -> 2-way conflicts only (free).
// ---------------------------------------------------------------------------
template <bool WRITE_F32, bool WRITE_BF16>
__global__ __launch_bounds__(256) void gemm_bf16(
    const u16* __restrict__ A1, const u16* __restrict__ A2,
    const u16* __restrict__ BT, const float* __restrict__ bias,
    float* __restrict__ Cf, u16* __restrict__ Cb, u16* __restrict__ Cb2,
    int nsplit, int M, int N, int K, int ldc) {
  __shared__ u16 As[128 * 64];  // 16 KB
  __shared__ u16 Bs[128 * 64];  // 16 KB
  const int tid  = threadIdx.x;
  const int lane = tid & 63;
  const int wid  = tid >> 6;
  const int bm = blockIdx.x * 128;
  const int bn = blockIdx.y * 128;
  const int wr = (wid >> 1) * 64;
  const int wc = (wid & 1) * 64;

  f32x4 acc[4][4];
#pragma unroll
  for (int m = 0; m < 4; ++m)
#pragma unroll
    for (int n = 0; n < 4; ++n) acc[m][n] = (f32x4){0.f, 0.f, 0.f, 0.f};

  const int srow = lane >> 3;  // 0..7
  const int slot = lane & 7;   // 16B slot in 128B row
  const size_t astride = (A2 != nullptr) ? 512 : (size_t)K;

  for (int k0 = 0; k0 < K; k0 += 64) {
    const u16* Ap = A1;
    int kof = k0;
    if (A2 != nullptr && k0 >= 512) { Ap = A2; kof = k0 - 512; }
#pragma unroll
    for (int t = 0; t < 4; ++t) {
      const int inst = wid * 4 + t;
      const int row  = inst * 8 + srow;
      const int scol = ((slot ^ (row & 7)) << 4);
      const int ar   = min(bm + row, M - 1);
      gload_lds16((const char*)Ap + ((size_t)ar * astride + kof) * 2 + scol,
                  (char*)As + inst * 1024);
    }
#pragma unroll
    for (int t = 0; t < 4; ++t) {
      const int inst = wid * 4 + t;
      const int row  = inst * 8 + srow;
      const int scol = ((slot ^ (row & 7)) << 4);
      const int bc   = min(bn + row, N - 1);
      gload_lds16((const char*)BT + ((size_t)bc * K + k0) * 2 + scol,
                  (char*)Bs + inst * 1024);
    }
    asm volatile("s_waitcnt vmcnt(0)" ::: "memory");
    __syncthreads();

#pragma unroll
    for (int kk = 0; kk < 2; ++kk) {
      bf16x8 af[4], bfr[4];
#pragma unroll
      for (int m = 0; m < 4; ++m) {
        const int r = wr + m * 16 + (lane & 15);
        const int s = kk * 4 + (lane >> 4);
        af[m] = *(const bf16x8*)((const char*)As + r * 128 + ((s ^ (r & 7)) << 4));
      }
#pragma unroll
      for (int n = 0; n < 4; ++n) {
        const int c = wc + n * 16 + (lane & 15);
        const int s = kk * 4 + (lane >> 4);
        bfr[n] = *(const bf16x8*)((const char*)Bs + c * 128 + ((s ^ (c & 7)) << 4));
      }
#pragma unroll
      for (int m = 0; m < 4; ++m)
#pragma unroll
        for (int n = 0; n < 4; ++n)
          acc[m][n] = __builtin_amdgcn_mfma_f32_16x16x32_bf16(af[m], bfr[n],
                                                              acc[m][n], 0, 0, 0);
    }
    __syncthreads();
  }

  // C/D layout: col = lane&15, row = (lane>>4)*4 + j  [m89/m91]
#pragma unroll
  for (int m = 0; m < 4; ++m) {
    const int row0 = bm + wr + m * 16 + ((lane >> 4) << 2);
#pragma unroll
    for (int n = 0; n < 4; ++n) {
      const int col = bn + wc + n * 16 + (lane & 15);
      if (col < N) {
        const float bv = (bias != nullptr) ? bias[col] : 0.f;
#pragma unroll
        for (int j = 0; j < 4; ++j) {
          const int r = row0 + j;
          if (r < M) {
            const float v = acc[m][n][j] + bv;
            if (WRITE_F32) Cf[(size_t)r * ldc + col] = v;
            if (WRITE_BF16) {
              u16* dstp = Cb;
              int c = col;
              if (Cb2 != nullptr && col >= nsplit) { dstp = Cb2; c = col - nsplit; }
              dstp[(size_t)r * ldc + c] = f2bf(v);
            }
          }
        }
      }
    }
  }
}

// ---------------------------------------------------------------------------
// Fused per-node GATv2 attention + residual + LayerNorm + ReLU.
// One block (256 thr = 4 waves) per dst node. Chunked online softmax:
// stage <=32 gathered xl rows in LDS, logits in-register, local max/denom,
// accumulate from LDS, then LN the (residual + attn-out) row in-block.
// ---------------------------------------------------------------------------
__global__ __launch_bounds__(256) void gat_fused_kernel(
    const u16* __restrict__ xl, const u16* __restrict__ xr,
    const float* __restrict__ ea, const int* __restrict__ src,
    const int* __restrict__ offs, const int* __restrict__ sorted,
    const float* __restrict__ We, const float* __restrict__ att,
    const float* __restrict__ bias, const float* __restrict__ lng,
    const float* __restrict__ lnb, float* __restrict__ hF,
    u16* __restrict__ hb) {
  __shared__ u16 rowsLDS[kChunk][kD];  // 32 KB gathered xl rows
  __shared__ float sLDS[kChunk];       // logits -> weights
  __shared__ int   svLDS[kChunk];
  __shared__ float2 eaLDS[kChunk];
  __shared__ float red_s[4], red_q[4];
  __shared__ float bc_m, bc_s;

  const int n = blockIdx.x;
  const int tid = threadIdx.x, wid = tid >> 6, lane = tid & 63;
  const int beg = offs[n], end = offs[n + 1];

  // per-lane dim group (8 dims) for the logit pass
  const int d8 = lane * 8;
  float r8[8], w0[8], w1[8], a8[8];
  {
    const u16x8 rv = *(const u16x8*)(xr + (size_t)n * kD + d8);
#pragma unroll
    for (int i = 0; i < 8; ++i) {
      r8[i] = bf2f(rv[i]);
      w0[i] = We[d8 + i];
      w1[i] = We[kD + d8 + i];
      a8[i] = att[d8 + i];
    }
  }

  const int d2 = tid * 2;  // accumulation dims
  float acc0 = 0.f, acc1 = 0.f;
  float m_run = -INFINITY, l_run = 0.f;

  for (int c0 = beg; c0 < end; c0 += kChunk) {
    const int cdeg = min(kChunk, end - c0);
    // --- metadata preload (parallel, breaks the pointer-chase chain)
    if (tid < cdeg) {
      const int e = sorted[c0 + tid];
      svLDS[tid] = src[e];
      eaLDS[tid] = *(const float2*)(ea + (size_t)e * 2);
    }
    __syncthreads();
    // --- pass 1: gather rows + logits (wave per edge, 8 dims/lane)
    for (int i = wid; i < cdeg; i += 4) {
      const int sv = svLDS[i];
      const float2 e2 = eaLDS[i];
      const u16x8 l8 = *(const u16x8*)(xl + (size_t)sv * kD + d8);
      *(u16x8*)(&rowsLDS[i][d8]) = l8;
      float s = 0.f;
#pragma unroll
      for (int j = 0; j < 8; ++j) {
        const float m = bf2f(l8[j]) + r8[j] + e2.x * w0[j] + e2.y * w1[j];
        s += a8[j] * (m >= 0.f ? m : kNegSlope * m);
      }
#pragma unroll
      for (int off = 32; off > 0; off >>= 1) s += __shfl_xor(s, off);
      if (lane == 0) sLDS[i] = s;
    }
    __syncthreads();
    // --- chunk max / exp / sum (wave 0; cdeg <= 32 fits one wave)
    if (wid == 0) {
      const float v = (lane < cdeg) ? sLDS[lane] : -INFINITY;
      float mx = v;
#pragma unroll
      for (int off = 32; off > 0; off >>= 1) mx = fmaxf(mx, __shfl_xor(mx, off));
      const float nm = fmaxf(m_run, mx);
      const float w = (lane < cdeg) ? __expf(v - nm) : 0.f;
      if (lane < cdeg) sLDS[lane] = w;
      float sm = w;
#pragma unroll
      for (int off = 32; off > 0; off >>= 1) sm += __shfl_xor(sm, off);
      if (lane == 0) { bc_m = nm; bc_s = sm; }
    }
    __syncthreads();
    const float nm = bc_m, csum = bc_s;
    const float scale = (m_run == -INFINITY) ? 0.f : __expf(m_run - nm);
    l_run = l_run * scale + csum;
    acc0 *= scale;
    acc1 *= scale;
#pragma unroll 4
    for (int i = 0; i < cdeg; ++i) {
      const float w = sLDS[i];
      const unsigned pv = *(const unsigned*)(&rowsLDS[i][d2]);
      acc0 += w * __uint_as_float(pv << 16);
      acc1 += w * __uint_as_float(pv & 0xffff0000u);
    }
    m_run = nm;
    __syncthreads();  // rows/sLDS reused next chunk
  }

  const float inv = 1.f / (l_run > 0.f ? l_run : 1.f);
  // --- fused residual + LayerNorm + ReLU
  const float2 hv = *(const float2*)(hF + (size_t)n * kD + d2);
  const float x0 = hv.x + acc0 * inv + bias[d2];
  const float x1 = hv.y + acc1 * inv + bias[d2 + 1];
  float sum = x0 + x1, sq = x0 * x0 + x1 * x1;
#pragma unroll
  for (int off = 32; off > 0; off >>= 1) {
    sum += __shfl_xor(sum, off);
    sq  += __shfl_xor(sq, off);
  }
  if (lane == 0) { red_s[wid] = sum; red_q[wid] = sq; }
  __syncthreads();
  sum = red_s[0] + red_s[1] + red_s[2] + red_s[3];
  sq  = red_q[0] + red_q[1] + red_q[2] + red_q[3];
  const float mean = sum * (1.f / kD);
  const float var  = sq * (1.f / kD) - mean * mean;
  const float rs = rsqrtf(var + kLnEps);
  float y0 = (x0 - mean) * rs * lng[d2]     + lnb[d2];
  float y1 = (x1 - mean) * rs * lng[d2 + 1] + lnb[d2 + 1];
  y0 = fmaxf(y0, 0.f);
  y1 = fmaxf(y1, 0.f);
  float2 o; o.x = y0; o.y = y1;
  *(float2*)(hF + (size_t)n * kD + d2) = o;
  const unsigned packed = (unsigned)f2bf(y0) | ((unsigned)f2bf(y1) << 16);
  *(unsigned*)(hb + (size_t)n * kD + d2) = packed;
}

// ---------------------------------------------------------------------------
// Batched transpose: dst[n][k] = bf16(src[k][n]); all jobs have N=512 cols.
// Grid (32,16,nJobs); jobs with K=512 use only bx<16.
// ---------------------------------------------------------------------------
struct TxJobs {
  const float* src[10];
  u16* dst[10];
  int K[10];
};

__global__ __launch_bounds__(256) void transpose_all_kernel(TxJobs jobs) {
  const int z = blockIdx.z;
  const int K = jobs.K[z];
  const int k0 = blockIdx.x * 32;
  if (k0 >= K) return;
  const int n0 = blockIdx.y * 32;
  const float* W = jobs.src[z];
  u16* WT = jobs.dst[z];
  __shared__ float t[32][33];
  const int lx = threadIdx.x & 31, ly = threadIdx.x >> 5;  // 32 x 8
#pragma unroll
  for (int r = 0; r < 32; r += 8)
    t[ly + r][lx] = W[(size_t)(k0 + ly + r) * 512 + n0 + lx];
  __syncthreads();
#pragma unroll
  for (int r = 0; r < 32; r += 8)
    WT[(size_t)(n0 + ly + r) * K + k0 + lx] = f2bf(t[lx][ly + r]);
}

__global__ void convert_bf16_kernel(const float* __restrict__ in,
                                    u16* __restrict__ out, int n4) {
  const int i = blockIdx.x * 256 + threadIdx.x;
  if (i >= n4) return;
  const float4 v = reinterpret_cast<const float4*>(in)[i];
  u16 o[4] = {f2bf(v.x), f2bf(v.y), f2bf(v.z), f2bf(v.w)};
  *reinterpret_cast<ulonglong1*>(out + (size_t)i * 4) =
      *reinterpret_cast<ulonglong1*>(o);
}

// catB[k][j] = j<512 ? bl[k][j] : br[k][j-512]
__global__ void catbias_kernel(const float* __restrict__ bl,
                               const float* __restrict__ br,
                               float* __restrict__ catB) {
  const int i = blockIdx.x * 256 + threadIdx.x;  // 3*1024
  if (i >= 3 * 1024) return;
  const int k = i >> 10, j = i & 1023;
  catB[i] = (j < 512) ? bl[k * 512 + j] : br[k * 512 + j - 512];
}

// ------------------------- CSR build helpers -------------------------------
__global__ void fill_i32(int* p, int v, int n) {
  const int i = blockIdx.x * 256 + threadIdx.x;
  if (i < n) p[i] = v;
}
__global__ void copy_i32(const int* a, int* b, int n) {
  const int i = blockIdx.x * 256 + threadIdx.x;
  if (i < n) b[i] = a[i];
}
__global__ void count_kernel(const int* __restrict__ dst, int* __restrict__ counts) {
  const int e = blockIdx.x * 256 + threadIdx.x;
  if (e < kE) atomicAdd(&counts[dst[e]], 1);
}
__global__ __launch_bounds__(1024) void scan_kernel(const int* __restrict__ counts,
                                                    int* __restrict__ offs, int n) {
  __shared__ int buf[1024];
  __shared__ int carry;
  const int tid = threadIdx.x;
  if (tid == 0) carry = 0;
  __syncthreads();
  for (int base = 0; base < n; base += 1024) {
    const int v = (base + tid < n) ? counts[base + tid] : 0;
    buf[tid] = v;
    __syncthreads();
    for (int off = 1; off < 1024; off <<= 1) {
      const int t = (tid >= off) ? buf[tid - off] : 0;
      __syncthreads();
      buf[tid] += t;
      __syncthreads();
    }
    if (base + tid < n) offs[base + tid] = carry + buf[tid] - v;
    __syncthreads();
    if (tid == 0) carry += buf[1023];
    __syncthreads();
  }
  if (tid == 0) offs[n] = carry;
}
__global__ void scatter_kernel(const int* __restrict__ dst, int* __restrict__ pos,
                               int* __restrict__ sorted) {
  const int e = blockIdx.x * 256 + threadIdx.x;
  if (e >= kE) return;
  const int p = atomicAdd(&pos[dst[e]], 1);
  sorted[p] = e;
}

}  // namespace

extern "C" void kernel_launch(void* const* d_in, const int* in_sizes, int n_in,
                              void* d_out, int out_size, void* d_ws, size_t ws_size,
                              hipStream_t stream) {
  const float* x         = (const float*)d_in[0];
  const float* edge_attr = (const float*)d_in[1];
  const float* emb_inv_W = (const float*)d_in[2];
  const float* emb_inv_b = (const float*)d_in[3];
  const float* emb_org_W = (const float*)d_in[4];
  const float* emb_org_b = (const float*)d_in[5];
  const float* gat_Wl    = (const float*)d_in[6];
  const float* gat_bl    = (const float*)d_in[7];
  const float* gat_Wr    = (const float*)d_in[8];
  const float* gat_br    = (const float*)d_in[9];
  const float* gat_We    = (const float*)d_in[10];
  const float* gat_att   = (const float*)d_in[11];
  const float* gat_bias  = (const float*)d_in[12];
  const float* ln_g      = (const float*)d_in[13];
  const float* ln_b      = (const float*)d_in[14];
  const float* lin0_W    = (const float*)d_in[15];
  const float* lin0_b    = (const float*)d_in[16];
  const float* lin1_W    = (const float*)d_in[17];
  const float* lin1_b    = (const float*)d_in[18];
  const int*   edge_idx  = (const int*)d_in[19];
  const int* src = edge_idx;
  const int* dst = edge_idx + kE;
  float* out = (float*)d_out;

  // ---- workspace layout (~86 MB) ----
  float* hF   = (float*)d_ws;          // [N,D] residual stream (f32)
  float* catB = hF + kND;              // [3,1024] concat gat biases
  u16* xb   = (u16*)(catB + 3072);     // [N,D] bf16(x)
  u16* hb0  = xb + kND;                // [N,D] bf16 initial embedding
  u16* hb   = hb0 + kND;               // [N,D] bf16 running h
  u16* xlB  = hb + kND;                // [N,D]
  u16* xrB  = xlB + kND;               // [N,D]
  u16* y0b  = xrB + kND;               // [4000,512]
  u16* y1b  = y0b + kNinv * kD;        // [3000,512]
  u16* embInvT = y1b + kNunk * kD;     // [512,512]
  u16* embOrgT = embInvT + 262144;
  u16* WlrT    = embOrgT + 262144;     // 3 x [1024,512] (WlT rows 0-511, WrT 512-1023)
  u16* lin0T   = WlrT + 3 * 524288;    // [512,1024]
  u16* lin1T   = lin0T + 524288;
  int* counts  = (int*)(lin1T + 524288);
  int* offs    = counts + kN;
  int* pos     = offs + kN + 1;
  int* sorted  = pos + kN;

  const dim3 blk(256);
  auto cdiv = [](int a, int b) { return (a + b - 1) / b; };

  // ---- 0. setup: batched weight transpose + x convert + concat bias
  {
    TxJobs j;
    j.src[0] = emb_inv_W;  j.dst[0] = embInvT;  j.K[0] = 512;
    j.src[1] = emb_org_W;  j.dst[1] = embOrgT;  j.K[1] = 512;
    for (int k = 0; k < 3; ++k) {
      j.src[2 + k] = gat_Wl + (size_t)k * kD * kD;
      j.dst[2 + k] = WlrT + (size_t)k * 524288;            // rows 0..511
      j.K[2 + k] = 512;
      j.src[5 + k] = gat_Wr + (size_t)k * kD * kD;
      j.dst[5 + k] = WlrT + (size_t)k * 524288 + 262144;   // rows 512..1023
      j.K[5 + k] = 512;
    }
    j.src[8] = lin0_W; j.dst[8] = lin0T; j.K[8] = 1024;
    j.src[9] = lin1_W; j.dst[9] = lin1T; j.K[9] = 1024;
    transpose_all_kernel<<<dim3(32, 16, 10), blk, 0, stream>>>(j);
  }
  convert_bf16_kernel<<<dim3(cdiv(kND / 4, 256)), blk, 0, stream>>>(x, xb, kND / 4);
  catbias_kernel<<<dim3(12), blk, 0, stream>>>(gat_bl, gat_br, catB);

  // ---- 1. embeddings -> hF (f32) + hb0 (bf16)
  gemm_bf16<true, true><<<dim3(cdiv(kNinv, 128), 4), blk, 0, stream>>>(
      xb, nullptr, embInvT, emb_inv_b, hF, hb0, nullptr, 0, kNinv, kD, kD, kD);
  gemm_bf16<true, true><<<dim3(cdiv(kN - kNinv, 128), 4), blk, 0, stream>>>(
      xb + (size_t)kNinv * kD, nullptr, embOrgT, emb_org_b,
      hF + (size_t)kNinv * kD, hb0 + (size_t)kNinv * kD, nullptr, 0,
      kN - kNinv, kD, kD, kD);

  // ---- 2. CSR over dst (reused by all 3 layers)
  fill_i32<<<dim3(cdiv(kN, 256)), blk, 0, stream>>>(counts, 0, kN);
  count_kernel<<<dim3(cdiv(kE, 256)), blk, 0, stream>>>(dst, counts);
  scan_kernel<<<dim3(1), dim3(1024), 0, stream>>>(counts, offs, kN);
  copy_i32<<<dim3(cdiv(kN, 256)), blk, 0, stream>>>(offs, pos, kN);
  scatter_kernel<<<dim3(cdiv(kE, 256)), blk, 0, stream>>>(dst, pos, sorted);

  // ---- 3. GAT layers: 1 fused lr-GEMM + 1 fused attention kernel each
  for (int k = 0; k < 3; ++k) {
    const u16* hIn = (k == 0) ? hb0 : hb;
    gemm_bf16<false, true><<<dim3(cdiv(kN, 128), 8), blk, 0, stream>>>(
        hIn, nullptr, WlrT + (size_t)k * 524288, catB + k * 1024,
        nullptr, xlB, xrB, 512, kN, 1024, kD, kD);
    gat_fused_kernel<<<dim3(kN), blk, 0, stream>>>(
        xlB, xrB, edge_attr, src, offs, sorted,
        gat_We + (size_t)k * 2 * kD, gat_att + (size_t)k * kD,
        gat_bias + (size_t)k * kD, ln_g + (size_t)k * kD,
        ln_b + (size_t)k * kD, hF, hb);
  }

  // ---- 4. heads via A-split ([hb0 | hb] along K): y0, y1 (bf16)
  gemm_bf16<false, true><<<dim3(cdiv(kNinv, 128), 4), blk, 0, stream>>>(
      hb0, hb, lin0T, lin0_b, nullptr, y0b, nullptr, 0, kNinv, kD, 2 * kD, kD);
  const size_t off = (size_t)(kN - kNunk) * kD;
  gemm_bf16<false, true><<<dim3(cdiv(kNunk, 128), 4), blk, 0, stream>>>(
      hb0 + off, hb + off, lin1T, lin1_b, nullptr, y1b, nullptr, 0,
      kNunk, kD, 2 * kD, kD);

  // ---- 5. out = y0 @ y1^T  [4000,3000]
  gemm_bf16<true, false><<<dim3(cdiv(kNinv, 128), cdiv(kNunk, 128)), blk, 0, stream>>>(
      y0b, nullptr, y1b, nullptr, out, nullptr, nullptr, 0,
      kNinv, kNunk, kD, kNunk);
}

// Round 4
// 460.379 us; speedup vs baseline: 3.1539x; 1.0303x over previous
//
#include <hip/hip_runtime.h>
#include <cstddef>
#include <cstdint>

namespace {

using u16 = unsigned short;
typedef __attribute__((ext_vector_type(8))) unsigned short u16x8;
typedef __attribute__((ext_vector_type(8))) short bf16x8;
typedef __attribute__((ext_vector_type(4))) float f32x4;

constexpr int kN    = 10000;   // nodes
constexpr int kE    = 160000;  // edges
constexpr int kD    = 512;     // feature dim
constexpr int kNinv = 4000;
constexpr int kNunk = 3000;
constexpr int kND   = kN * kD;
constexpr int kChunk = 32;     // fused-attn LDS row capacity (online softmax chunk)
constexpr float kNegSlope = 0.2f;
constexpr float kLnEps    = 1e-5f;

__device__ __forceinline__ float bf2f(u16 u) {
  return __uint_as_float((unsigned)u << 16);
}
__device__ __forceinline__ u16 f2bf(float f) {
  unsigned u = __float_as_uint(f);
  return (u16)((u + 0x7FFFu + ((u >> 16) & 1u)) >> 16);  // RNE
}

__device__ __forceinline__ void gload_lds16(const void* g, void* l) {
  __builtin_amdgcn_global_load_lds(
      (const __attribute__((address_space(1))) void*)(unsigned long long)(uintptr_t)g,
      (__attribute__((address_space(3))) void*)(unsigned)(uintptr_t)l,
      16, 0, 0);
}

// ---------------------------------------------------------------------------
// bf16 MFMA GEMM: C[M,N] = A[M,K](bf16) * BT[N,K]^T(bf16) (+ bias)
//   A = [A1 | A2] split along K at 512 when A2 != nullptr (row stride 512 each);
//   else A1 row stride K.
//   Cb2/nsplit: bf16 cols >= nsplit go to Cb2 (col-nsplit), both ldc wide.
// 128x128 tile, BK=64, 256 thr = 4 waves (2x2), 16x16x32 MFMA.
// global_load_lds(16B), XOR swizzle (both-sides: pre-swizzled source + swizzled
// ds_read) -> 2-way conflicts only (free).
// ---------------------------------------------------------------------------
template <bool WRITE_F32, bool WRITE_BF16>
__global__ __launch_bounds__(256) void gemm_bf16(
    const u16* __restrict__ A1, const u16* __restrict__ A2,
    const u16* __restrict__ BT, const float* __restrict__ bias,
    float* __restrict__ Cf, u16* __restrict__ Cb, u16* __restrict__ Cb2,
    int nsplit, int M, int N, int K, int ldc) {
  __shared__ u16 As[128 * 64];  // 16 KB
  __shared__ u16 Bs[128 * 64];  // 16 KB
  const int tid  = threadIdx.x;
  const int lane = tid & 63;
  const int wid  = tid >> 6;
  const int bm = blockIdx.x * 128;
  const int bn = blockIdx.y * 128;
  const int wr = (wid >> 1) * 64;
  const int wc = (wid & 1) * 64;

  f32x4 acc[4][4];
#pragma unroll
  for (int m = 0; m < 4; ++m)
#pragma unroll
    for (int n = 0; n < 4; ++n) acc[m][n] = (f32x4){0.f, 0.f, 0.f, 0.f};

  const int srow = lane >> 3;  // 0..7
  const int slot = lane & 7;   // 16B slot in 128B row
  const size_t astride = (A2 != nullptr) ? 512 : (size_t)K;

  for (int k0 = 0; k0 < K; k0 += 64) {
    const u16* Ap = A1;
    int kof = k0;
    if (A2 != nullptr && k0 >= 512) { Ap = A2; kof = k0 - 512; }
#pragma unroll
    for (int t = 0; t < 4; ++t) {
      const int inst = wid * 4 + t;
      const int row  = inst * 8 + srow;
      const int scol = ((slot ^ (row & 7)) << 4);
      const int ar   = min(bm + row, M - 1);
      gload_lds16((const char*)Ap + ((size_t)ar * astride + kof) * 2 + scol,
                  (char*)As + inst * 1024);
    }
#pragma unroll
    for (int t = 0; t < 4; ++t) {
      const int inst = wid * 4 + t;
      const int row  = inst * 8 + srow;
      const int scol = ((slot ^ (row & 7)) << 4);
      const int bc   = min(bn + row, N - 1);
      gload_lds16((const char*)BT + ((size_t)bc * K + k0) * 2 + scol,
                  (char*)Bs + inst * 1024);
    }
    asm volatile("s_waitcnt vmcnt(0)" ::: "memory");
    __syncthreads();

#pragma unroll
    for (int kk = 0; kk < 2; ++kk) {
      bf16x8 af[4], bfr[4];
#pragma unroll
      for (int m = 0; m < 4; ++m) {
        const int r = wr + m * 16 + (lane & 15);
        const int s = kk * 4 + (lane >> 4);
        af[m] = *(const bf16x8*)((const char*)As + r * 128 + ((s ^ (r & 7)) << 4));
      }
#pragma unroll
      for (int n = 0; n < 4; ++n) {
        const int c = wc + n * 16 + (lane & 15);
        const int s = kk * 4 + (lane >> 4);
        bfr[n] = *(const bf16x8*)((const char*)Bs + c * 128 + ((s ^ (c & 7)) << 4));
      }
#pragma unroll
      for (int m = 0; m < 4; ++m)
#pragma unroll
        for (int n = 0; n < 4; ++n)
          acc[m][n] = __builtin_amdgcn_mfma_f32_16x16x32_bf16(af[m], bfr[n],
                                                              acc[m][n], 0, 0, 0);
    }
    __syncthreads();
  }

  // C/D layout: col = lane&15, row = (lane>>4)*4 + j  [m89/m91]
#pragma unroll
  for (int m = 0; m < 4; ++m) {
    const int row0 = bm + wr + m * 16 + ((lane >> 4) << 2);
#pragma unroll
    for (int n = 0; n < 4; ++n) {
      const int col = bn + wc + n * 16 + (lane & 15);
      if (col < N) {
        const float bv = (bias != nullptr) ? bias[col] : 0.f;
#pragma unroll
        for (int j = 0; j < 4; ++j) {
          const int r = row0 + j;
          if (r < M) {
            const float v = acc[m][n][j] + bv;
            if (WRITE_F32) Cf[(size_t)r * ldc + col] = v;
            if (WRITE_BF16) {
              u16* dstp = Cb;
              int c = col;
              if (Cb2 != nullptr && col >= nsplit) { dstp = Cb2; c = col - nsplit; }
              dstp[(size_t)r * ldc + c] = f2bf(v);
            }
          }
        }
      }
    }
  }
}

// ---------------------------------------------------------------------------
// Fused per-node GATv2 attention + residual + LayerNorm + ReLU.
// One block (256 thr = 4 waves) per dst node. Chunked online softmax.
// Pass structure per chunk:
//   (a) metadata preload, (b) PREFETCH all <=32 xl rows via global_load_lds
//   back-to-back (8 outstanding/wave, 32/block -> one HBM latency round
//   instead of four), (c) logits from LDS, (d) chunk softmax, (e) accumulate.
// ---------------------------------------------------------------------------
__global__ __launch_bounds__(256) void gat_fused_kernel(
    const u16* __restrict__ xl, const u16* __restrict__ xr,
    const float* __restrict__ ea, const int* __restrict__ src,
    const int* __restrict__ offs, const int* __restrict__ sorted,
    const float* __restrict__ We, const float* __restrict__ att,
    const float* __restrict__ bias, const float* __restrict__ lng,
    const float* __restrict__ lnb, float* __restrict__ hF,
    u16* __restrict__ hb) {
  __shared__ u16 rowsLDS[kChunk][kD];  // 32 KB gathered xl rows
  __shared__ float sLDS[kChunk];       // logits -> weights
  __shared__ int   svLDS[kChunk];
  __shared__ float2 eaLDS[kChunk];
  __shared__ float red_s[4], red_q[4];
  __shared__ float bc_m, bc_s;

  const int n = blockIdx.x;
  const int tid = threadIdx.x, wid = tid >> 6, lane = tid & 63;
  const int beg = offs[n], end = offs[n + 1];

  // per-lane dim group (8 dims) for the logit pass
  const int d8 = lane * 8;
  float r8[8], w0[8], w1[8], a8[8];
  {
    const u16x8 rv = *(const u16x8*)(xr + (size_t)n * kD + d8);
#pragma unroll
    for (int i = 0; i < 8; ++i) {
      r8[i] = bf2f(rv[i]);
      w0[i] = We[d8 + i];
      w1[i] = We[kD + d8 + i];
      a8[i] = att[d8 + i];
    }
  }

  const int d2 = tid * 2;  // accumulation dims
  float acc0 = 0.f, acc1 = 0.f;
  float m_run = -INFINITY, l_run = 0.f;

  for (int c0 = beg; c0 < end; c0 += kChunk) {
    const int cdeg = min(kChunk, end - c0);
    // --- (a) metadata preload (parallel, breaks the pointer-chase chain)
    if (tid < cdeg) {
      const int e = sorted[c0 + tid];
      svLDS[tid] = src[e];
      eaLDS[tid] = *(const float2*)(ea + (size_t)e * 2);
    }
    __syncthreads();
    // --- (b) prefetch rows into LDS, all loads in flight at once.
    //     LDS dest is wave-uniform base + lane*16 (linear row), source is
    //     per-lane global addr -> exact global_load_lds fit.
    for (int i = wid; i < cdeg; i += 4) {
      gload_lds16(xl + (size_t)svLDS[i] * kD + d8, (char*)&rowsLDS[i][0]);
    }
    asm volatile("s_waitcnt vmcnt(0)" ::: "memory");
    __syncthreads();
    // --- (c) logits from LDS (wave per edge, 8 dims/lane, b128 stride-1)
    for (int i = wid; i < cdeg; i += 4) {
      const float2 e2 = eaLDS[i];
      const u16x8 l8 = *(const u16x8*)(&rowsLDS[i][d8]);
      float s = 0.f;
#pragma unroll
      for (int j = 0; j < 8; ++j) {
        const float m = bf2f(l8[j]) + r8[j] + e2.x * w0[j] + e2.y * w1[j];
        s += a8[j] * (m >= 0.f ? m : kNegSlope * m);
      }
#pragma unroll
      for (int off = 32; off > 0; off >>= 1) s += __shfl_xor(s, off);
      if (lane == 0) sLDS[i] = s;
    }
    __syncthreads();
    // --- (d) chunk max / exp / sum (wave 0; cdeg <= 32 fits one wave)
    if (wid == 0) {
      const float v = (lane < cdeg) ? sLDS[lane] : -INFINITY;
      float mx = v;
#pragma unroll
      for (int off = 32; off > 0; off >>= 1) mx = fmaxf(mx, __shfl_xor(mx, off));
      const float nm = fmaxf(m_run, mx);
      const float w = (lane < cdeg) ? __expf(v - nm) : 0.f;
      if (lane < cdeg) sLDS[lane] = w;
      float sm = w;
#pragma unroll
      for (int off = 32; off > 0; off >>= 1) sm += __shfl_xor(sm, off);
      if (lane == 0) { bc_m = nm; bc_s = sm; }
    }
    __syncthreads();
    const float nm = bc_m, csum = bc_s;
    const float scale = (m_run == -INFINITY) ? 0.f : __expf(m_run - nm);
    l_run = l_run * scale + csum;
    acc0 *= scale;
    acc1 *= scale;
    // --- (e) accumulate (thread owns 2 dims; 2-way LDS alias = free)
#pragma unroll 4
    for (int i = 0; i < cdeg; ++i) {
      const float w = sLDS[i];
      const unsigned pv = *(const unsigned*)(&rowsLDS[i][d2]);
      acc0 += w * __uint_as_float(pv << 16);
      acc1 += w * __uint_as_float(pv & 0xffff0000u);
    }
    m_run = nm;
    __syncthreads();  // rows/sLDS reused next chunk
  }

  const float inv = 1.f / (l_run > 0.f ? l_run : 1.f);
  // --- fused residual + LayerNorm + ReLU
  const float2 hv = *(const float2*)(hF + (size_t)n * kD + d2);
  const float x0 = hv.x + acc0 * inv + bias[d2];
  const float x1 = hv.y + acc1 * inv + bias[d2 + 1];
  float sum = x0 + x1, sq = x0 * x0 + x1 * x1;
#pragma unroll
  for (int off = 32; off > 0; off >>= 1) {
    sum += __shfl_xor(sum, off);
    sq  += __shfl_xor(sq, off);
  }
  if (lane == 0) { red_s[wid] = sum; red_q[wid] = sq; }
  __syncthreads();
  sum = red_s[0] + red_s[1] + red_s[2] + red_s[3];
  sq  = red_q[0] + red_q[1] + red_q[2] + red_q[3];
  const float mean = sum * (1.f / kD);
  const float var  = sq * (1.f / kD) - mean * mean;
  const float rs = rsqrtf(var + kLnEps);
  float y0 = (x0 - mean) * rs * lng[d2]     + lnb[d2];
  float y1 = (x1 - mean) * rs * lng[d2 + 1] + lnb[d2 + 1];
  y0 = fmaxf(y0, 0.f);
  y1 = fmaxf(y1, 0.f);
  float2 o; o.x = y0; o.y = y1;
  *(float2*)(hF + (size_t)n * kD + d2) = o;
  const unsigned packed = (unsigned)f2bf(y0) | ((unsigned)f2bf(y1) << 16);
  *(unsigned*)(hb + (size_t)n * kD + d2) = packed;
}

// ---------------------------------------------------------------------------
// Batched transpose: dst[n][k] = bf16(src[k][n]); all jobs have N=512 cols.
// Grid (32,16,nJobs); jobs with K=512 use only bx<16.
// ---------------------------------------------------------------------------
struct TxJobs {
  const float* src[10];
  u16* dst[10];
  int K[10];
};

__global__ __launch_bounds__(256) void transpose_all_kernel(TxJobs jobs) {
  const int z = blockIdx.z;
  const int K = jobs.K[z];
  const int k0 = blockIdx.x * 32;
  if (k0 >= K) return;
  const int n0 = blockIdx.y * 32;
  const float* W = jobs.src[z];
  u16* WT = jobs.dst[z];
  __shared__ float t[32][33];
  const int lx = threadIdx.x & 31, ly = threadIdx.x >> 5;  // 32 x 8
#pragma unroll
  for (int r = 0; r < 32; r += 8)
    t[ly + r][lx] = W[(size_t)(k0 + ly + r) * 512 + n0 + lx];
  __syncthreads();
#pragma unroll
  for (int r = 0; r < 32; r += 8)
    WT[(size_t)(n0 + ly + r) * K + k0 + lx] = f2bf(t[lx][ly + r]);
}

__global__ void convert_bf16_kernel(const float* __restrict__ in,
                                    u16* __restrict__ out, int n4) {
  const int i = blockIdx.x * 256 + threadIdx.x;
  if (i >= n4) return;
  const float4 v = reinterpret_cast<const float4*>(in)[i];
  u16 o[4] = {f2bf(v.x), f2bf(v.y), f2bf(v.z), f2bf(v.w)};
  *reinterpret_cast<ulonglong1*>(out + (size_t)i * 4) =
      *reinterpret_cast<ulonglong1*>(o);
}

// catB[k][j] = j<512 ? bl[k][j] : br[k][j-512]
__global__ void catbias_kernel(const float* __restrict__ bl,
                               const float* __restrict__ br,
                               float* __restrict__ catB) {
  const int i = blockIdx.x * 256 + threadIdx.x;  // 3*1024
  if (i >= 3 * 1024) return;
  const int k = i >> 10, j = i & 1023;
  catB[i] = (j < 512) ? bl[k * 512 + j] : br[k * 512 + j - 512];
}

// ------------------------- CSR build helpers -------------------------------
__global__ void fill_i32(int* p, int v, int n) {
  const int i = blockIdx.x * 256 + threadIdx.x;
  if (i < n) p[i] = v;
}
__global__ void copy_i32(const int* a, int* b, int n) {
  const int i = blockIdx.x * 256 + threadIdx.x;
  if (i < n) b[i] = a[i];
}
__global__ void count_kernel(const int* __restrict__ dst, int* __restrict__ counts) {
  const int e = blockIdx.x * 256 + threadIdx.x;
  if (e < kE) atomicAdd(&counts[dst[e]], 1);
}
__global__ __launch_bounds__(1024) void scan_kernel(const int* __restrict__ counts,
                                                    int* __restrict__ offs, int n) {
  __shared__ int buf[1024];
  __shared__ int carry;
  const int tid = threadIdx.x;
  if (tid == 0) carry = 0;
  __syncthreads();
  for (int base = 0; base < n; base += 1024) {
    const int v = (base + tid < n) ? counts[base + tid] : 0;
    buf[tid] = v;
    __syncthreads();
    for (int off = 1; off < 1024; off <<= 1) {
      const int t = (tid >= off) ? buf[tid - off] : 0;
      __syncthreads();
      buf[tid] += t;
      __syncthreads();
    }
    if (base + tid < n) offs[base + tid] = carry + buf[tid] - v;
    __syncthreads();
    if (tid == 0) carry += buf[1023];
    __syncthreads();
  }
  if (tid == 0) offs[n] = carry;
}
__global__ void scatter_kernel(const int* __restrict__ dst, int* __restrict__ pos,
                               int* __restrict__ sorted) {
  const int e = blockIdx.x * 256 + threadIdx.x;
  if (e >= kE) return;
  const int p = atomicAdd(&pos[dst[e]], 1);
  sorted[p] = e;
}

}  // namespace

extern "C" void kernel_launch(void* const* d_in, const int* in_sizes, int n_in,
                              void* d_out, int out_size, void* d_ws, size_t ws_size,
                              hipStream_t stream) {
  const float* x         = (const float*)d_in[0];
  const float* edge_attr = (const float*)d_in[1];
  const float* emb_inv_W = (const float*)d_in[2];
  const float* emb_inv_b = (const float*)d_in[3];
  const float* emb_org_W = (const float*)d_in[4];
  const float* emb_org_b = (const float*)d_in[5];
  const float* gat_Wl    = (const float*)d_in[6];
  const float* gat_bl    = (const float*)d_in[7];
  const float* gat_Wr    = (const float*)d_in[8];
  const float* gat_br    = (const float*)d_in[9];
  const float* gat_We    = (const float*)d_in[10];
  const float* gat_att   = (const float*)d_in[11];
  const float* gat_bias  = (const float*)d_in[12];
  const float* ln_g      = (const float*)d_in[13];
  const float* ln_b      = (const float*)d_in[14];
  const float* lin0_W    = (const float*)d_in[15];
  const float* lin0_b    = (const float*)d_in[16];
  const float* lin1_W    = (const float*)d_in[17];
  const float* lin1_b    = (const float*)d_in[18];
  const int*   edge_idx  = (const int*)d_in[19];
  const int* src = edge_idx;
  const int* dst = edge_idx + kE;
  float* out = (float*)d_out;

  // ---- workspace layout (~86 MB) ----
  float* hF   = (float*)d_ws;          // [N,D] residual stream (f32)
  float* catB = hF + kND;              // [3,1024] concat gat biases
  u16* xb   = (u16*)(catB + 3072);     // [N,D] bf16(x)
  u16* hb0  = xb + kND;                // [N,D] bf16 initial embedding
  u16* hb   = hb0 + kND;               // [N,D] bf16 running h
  u16* xlB  = hb + kND;                // [N,D]
  u16* xrB  = xlB + kND;               // [N,D]
  u16* y0b  = xrB + kND;               // [4000,512]
  u16* y1b  = y0b + kNinv * kD;        // [3000,512]
  u16* embInvT = y1b + kNunk * kD;     // [512,512]
  u16* embOrgT = embInvT + 262144;
  u16* WlrT    = embOrgT + 262144;     // 3 x [1024,512] (WlT rows 0-511, WrT 512-1023)
  u16* lin0T   = WlrT + 3 * 524288;    // [512,1024]
  u16* lin1T   = lin0T + 524288;
  int* counts  = (int*)(lin1T + 524288);
  int* offs    = counts + kN;
  int* pos     = offs + kN + 1;
  int* sorted  = pos + kN;

  const dim3 blk(256);
  auto cdiv = [](int a, int b) { return (a + b - 1) / b; };

  // ---- 0. setup: batched weight transpose + x convert + concat bias
  {
    TxJobs j;
    j.src[0] = emb_inv_W;  j.dst[0] = embInvT;  j.K[0] = 512;
    j.src[1] = emb_org_W;  j.dst[1] = embOrgT;  j.K[1] = 512;
    for (int k = 0; k < 3; ++k) {
      j.src[2 + k] = gat_Wl + (size_t)k * kD * kD;
      j.dst[2 + k] = WlrT + (size_t)k * 524288;            // rows 0..511
      j.K[2 + k] = 512;
      j.src[5 + k] = gat_Wr + (size_t)k * kD * kD;
      j.dst[5 + k] = WlrT + (size_t)k * 524288 + 262144;   // rows 512..1023
      j.K[5 + k] = 512;
    }
    j.src[8] = lin0_W; j.dst[8] = lin0T; j.K[8] = 1024;
    j.src[9] = lin1_W; j.dst[9] = lin1T; j.K[9] = 1024;
    transpose_all_kernel<<<dim3(32, 16, 10), blk, 0, stream>>>(j);
  }
  convert_bf16_kernel<<<dim3(cdiv(kND / 4, 256)), blk, 0, stream>>>(x, xb, kND / 4);
  catbias_kernel<<<dim3(12), blk, 0, stream>>>(gat_bl, gat_br, catB);

  // ---- 1. embeddings -> hF (f32) + hb0 (bf16)
  gemm_bf16<true, true><<<dim3(cdiv(kNinv, 128), 4), blk, 0, stream>>>(
      xb, nullptr, embInvT, emb_inv_b, hF, hb0, nullptr, 0, kNinv, kD, kD, kD);
  gemm_bf16<true, true><<<dim3(cdiv(kN - kNinv, 128), 4), blk, 0, stream>>>(
      xb + (size_t)kNinv * kD, nullptr, embOrgT, emb_org_b,
      hF + (size_t)kNinv * kD, hb0 + (size_t)kNinv * kD, nullptr, 0,
      kN - kNinv, kD, kD, kD);

  // ---- 2. CSR over dst (reused by all 3 layers)
  fill_i32<<<dim3(cdiv(kN, 256)), blk, 0, stream>>>(counts, 0, kN);
  count_kernel<<<dim3(cdiv(kE, 256)), blk, 0, stream>>>(dst, counts);
  scan_kernel<<<dim3(1), dim3(1024), 0, stream>>>(counts, offs, kN);
  copy_i32<<<dim3(cdiv(kN, 256)), blk, 0, stream>>>(offs, pos, kN);
  scatter_kernel<<<dim3(cdiv(kE, 256)), blk, 0, stream>>>(dst, pos, sorted);

  // ---- 3. GAT layers: 1 fused lr-GEMM + 1 fused attention kernel each
  for (int k = 0; k < 3; ++k) {
    const u16* hIn = (k == 0) ? hb0 : hb;
    gemm_bf16<false, true><<<dim3(cdiv(kN, 128), 8), blk, 0, stream>>>(
        hIn, nullptr, WlrT + (size_t)k * 524288, catB + k * 1024,
        nullptr, xlB, xrB, 512, kN, 1024, kD, kD);
    gat_fused_kernel<<<dim3(kN), blk, 0, stream>>>(
        xlB, xrB, edge_attr, src, offs, sorted,
        gat_We + (size_t)k * 2 * kD, gat_att + (size_t)k * kD,
        gat_bias + (size_t)k * kD, ln_g + (size_t)k * kD,
        ln_b + (size_t)k * kD, hF, hb);
  }

  // ---- 4. heads via A-split ([hb0 | hb] along K): y0, y1 (bf16)
  gemm_bf16<false, true><<<dim3(cdiv(kNinv, 128), 4), blk, 0, stream>>>(
      hb0, hb, lin0T, lin0_b, nullptr, y0b, nullptr, 0, kNinv, kD, 2 * kD, kD);
  const size_t off = (size_t)(kN - kNunk) * kD;
  gemm_bf16<false, true><<<dim3(cdiv(kNunk, 128), 4), blk, 0, stream>>>(
      hb0 + off, hb + off, lin1T, lin1_b, nullptr, y1b, nullptr, 0,
      kNunk, kD, 2 * kD, kD);

  // ---- 5. out = y0 @ y1^T  [4000,3000]
  gemm_bf16<true, false><<<dim3(cdiv(kNinv, 128), cdiv(kNunk, 128)), blk, 0, stream>>>(
      y0b, nullptr, y1b, nullptr, out, nullptr, nullptr, 0,
      kNinv, kNunk, kD, kNunk);
}

// Round 5
// 439.842 us; speedup vs baseline: 3.3011x; 1.0467x over previous
//
#include <hip/hip_runtime.h>
#include <cstddef>
#include <cstdint>

namespace {

using u16 = unsigned short;
typedef __attribute__((ext_vector_type(8))) unsigned short u16x8;
typedef __attribute__((ext_vector_type(8))) short bf16x8;
typedef __attribute__((ext_vector_type(4))) float f32x4;

constexpr int kN    = 10000;   // nodes
constexpr int kE    = 160000;  // edges
constexpr int kD    = 512;     // feature dim
constexpr int kNinv = 4000;
constexpr int kNunk = 3000;
constexpr int kND   = kN * kD;
constexpr float kNegSlope = 0.2f;
constexpr float kLnEps    = 1e-5f;

__device__ __forceinline__ float bf2f(u16 u) {
  return __uint_as_float((unsigned)u << 16);
}
__device__ __forceinline__ u16 f2bf(float f) {
  unsigned u = __float_as_uint(f);
  return (u16)((u + 0x7FFFu + ((u >> 16) & 1u)) >> 16);  // RNE
}

__device__ __forceinline__ void gload_lds16(const void* g, void* l) {
  __builtin_amdgcn_global_load_lds(
      (const __attribute__((address_space(1))) void*)(unsigned long long)(uintptr_t)g,
      (__attribute__((address_space(3))) void*)(unsigned)(uintptr_t)l,
      16, 0, 0);
}

// ---------------------------------------------------------------------------
// bf16 MFMA GEMM: C[M,N] = A[M,K](bf16) * BT[N,K]^T(bf16) (+ bias)
//   A = [A1 | A2] split along K at 512 when A2 != nullptr (row stride 512 each);
//   else A1 row stride K.
//   Cb2/nsplit: bf16 cols >= nsplit go to Cb2 (col-nsplit), both ldc wide.
// 128x128 tile, BK=64, 256 thr = 4 waves (2x2), 16x16x32 MFMA.
// global_load_lds(16B), XOR swizzle (both-sides: pre-swizzled source + swizzled
// ds_read) -> 2-way conflicts only (free).
// ---------------------------------------------------------------------------
template <bool WRITE_F32, bool WRITE_BF16>
__global__ __launch_bounds__(256) void gemm_bf16(
    const u16* __restrict__ A1, const u16* __restrict__ A2,
    const u16* __restrict__ BT, const float* __restrict__ bias,
    float* __restrict__ Cf, u16* __restrict__ Cb, u16* __restrict__ Cb2,
    int nsplit, int M, int N, int K, int ldc) {
  __shared__ u16 As[128 * 64];  // 16 KB
  __shared__ u16 Bs[128 * 64];  // 16 KB
  const int tid  = threadIdx.x;
  const int lane = tid & 63;
  const int wid  = tid >> 6;
  const int bm = blockIdx.x * 128;
  const int bn = blockIdx.y * 128;
  const int wr = (wid >> 1) * 64;
  const int wc = (wid & 1) * 64;

  f32x4 acc[4][4];
#pragma unroll
  for (int m = 0; m < 4; ++m)
#pragma unroll
    for (int n = 0; n < 4; ++n) acc[m][n] = (f32x4){0.f, 0.f, 0.f, 0.f};

  const int srow = lane >> 3;  // 0..7
  const int slot = lane & 7;   // 16B slot in 128B row
  const size_t astride = (A2 != nullptr) ? 512 : (size_t)K;

  for (int k0 = 0; k0 < K; k0 += 64) {
    const u16* Ap = A1;
    int kof = k0;
    if (A2 != nullptr && k0 >= 512) { Ap = A2; kof = k0 - 512; }
#pragma unroll
    for (int t = 0; t < 4; ++t) {
      const int inst = wid * 4 + t;
      const int row  = inst * 8 + srow;
      const int scol = ((slot ^ (row & 7)) << 4);
      const int ar   = min(bm + row, M - 1);
      gload_lds16((const char*)Ap + ((size_t)ar * astride + kof) * 2 + scol,
                  (char*)As + inst * 1024);
    }
#pragma unroll
    for (int t = 0; t < 4; ++t) {
      const int inst = wid * 4 + t;
      const int row  = inst * 8 + srow;
      const int scol = ((slot ^ (row & 7)) << 4);
      const int bc   = min(bn + row, N - 1);
      gload_lds16((const char*)BT + ((size_t)bc * K + k0) * 2 + scol,
                  (char*)Bs + inst * 1024);
    }
    asm volatile("s_waitcnt vmcnt(0)" ::: "memory");
    __syncthreads();

#pragma unroll
    for (int kk = 0; kk < 2; ++kk) {
      bf16x8 af[4], bfr[4];
#pragma unroll
      for (int m = 0; m < 4; ++m) {
        const int r = wr + m * 16 + (lane & 15);
        const int s = kk * 4 + (lane >> 4);
        af[m] = *(const bf16x8*)((const char*)As + r * 128 + ((s ^ (r & 7)) << 4));
      }
#pragma unroll
      for (int n = 0; n < 4; ++n) {
        const int c = wc + n * 16 + (lane & 15);
        const int s = kk * 4 + (lane >> 4);
        bfr[n] = *(const bf16x8*)((const char*)Bs + c * 128 + ((s ^ (c & 7)) << 4));
      }
#pragma unroll
      for (int m = 0; m < 4; ++m)
#pragma unroll
        for (int n = 0; n < 4; ++n)
          acc[m][n] = __builtin_amdgcn_mfma_f32_16x16x32_bf16(af[m], bfr[n],
                                                              acc[m][n], 0, 0, 0);
    }
    __syncthreads();
  }

  // C/D layout: col = lane&15, row = (lane>>4)*4 + j  [m89/m91]
#pragma unroll
  for (int m = 0; m < 4; ++m) {
    const int row0 = bm + wr + m * 16 + ((lane >> 4) << 2);
#pragma unroll
    for (int n = 0; n < 4; ++n) {
      const int col = bn + wc + n * 16 + (lane & 15);
      if (col < N) {
        const float bv = (bias != nullptr) ? bias[col] : 0.f;
#pragma unroll
        for (int j = 0; j < 4; ++j) {
          const int r = row0 + j;
          if (r < M) {
            const float v = acc[m][n][j] + bv;
            if (WRITE_F32) Cf[(size_t)r * ldc + col] = v;
            if (WRITE_BF16) {
              u16* dstp = Cb;
              int c = col;
              if (Cb2 != nullptr && col >= nsplit) { dstp = Cb2; c = col - nsplit; }
              dstp[(size_t)r * ldc + c] = f2bf(v);
            }
          }
        }
      }
    }
  }
}

// ---------------------------------------------------------------------------
// Fused per-node GATv2 attention + residual + LayerNorm + ReLU.
// ONE WAVE PER NODE: zero LDS, zero barriers. 64 lanes x 8 dims = 512.
// Node state (xr row, We/att slices, fp32 accumulator) lives in registers.
// Edge metadata (<=64 edges) loaded once, broadcast per-edge via shfl.
// Per-edge: one coalesced 1KB xl-row wave-load consumed twice in registers
// (logit dot + accumulate) with per-edge online softmax; next row is
// issued before the shuffle-reduce chain (1-deep software pipeline).
// ---------------------------------------------------------------------------
__global__ __launch_bounds__(256) void gat_fused_kernel(
    const u16* __restrict__ xl, const u16* __restrict__ xr,
    const float* __restrict__ ea, const int* __restrict__ src,
    const int* __restrict__ offs, const int* __restrict__ sorted,
    const float* __restrict__ We, const float* __restrict__ att,
    const float* __restrict__ bias, const float* __restrict__ lng,
    const float* __restrict__ lnb, float* __restrict__ hF,
    u16* __restrict__ hb) {
  const int tid = threadIdx.x, wid = tid >> 6, lane = tid & 63;
  const int n = blockIdx.x * 4 + wid;
  if (n >= kN) return;
  const int d8 = lane * 8;

  // ---- per-node register state
  float r8[8], w0[8], w1[8], a8[8];
  {
    const u16x8 rv = *(const u16x8*)(xr + (size_t)n * kD + d8);
#pragma unroll
    for (int i = 0; i < 8; ++i) {
      r8[i] = bf2f(rv[i]);
      w0[i] = We[d8 + i];
      w1[i] = We[kD + d8 + i];
      a8[i] = att[d8 + i];
    }
  }

  float acc[8];
#pragma unroll
  for (int j = 0; j < 8; ++j) acc[j] = 0.f;
  float m_run = -INFINITY, l_run = 0.f;

  const int beg = offs[n], end = offs[n + 1];
  for (int base = beg; base < end; base += 64) {
    const int cnt = min(64, end - base);
    // metadata: lane i holds edge i's (src, ea) — one parallel round
    const int e  = sorted[base + ((lane < cnt) ? lane : 0)];
    const int sv = src[e];
    const float2 e2 = *(const float2*)(ea + (size_t)e * 2);

    u16x8 row = *(const u16x8*)(xl + (size_t)__shfl(sv, 0) * kD + d8);
    for (int i = 0; i < cnt; ++i) {
      u16x8 nrow = row;
      if (i + 1 < cnt) {  // issue next row before the reduce chain
        nrow = *(const u16x8*)(xl + (size_t)__shfl(sv, i + 1) * kD + d8);
      }
      const float ex = __shfl(e2.x, i), ey = __shfl(e2.y, i);
      float s = 0.f;
#pragma unroll
      for (int j = 0; j < 8; ++j) {
        const float m = bf2f(row[j]) + r8[j] + ex * w0[j] + ey * w1[j];
        s += a8[j] * (m >= 0.f ? m : kNegSlope * m);
      }
#pragma unroll
      for (int off = 32; off > 0; off >>= 1) s += __shfl_xor(s, off);
      const float nm = fmaxf(m_run, s);
      const float sc = __expf(m_run - nm);  // first edge: exp(-inf)=0
      const float w  = __expf(s - nm);
      l_run = l_run * sc + w;
#pragma unroll
      for (int j = 0; j < 8; ++j) acc[j] = acc[j] * sc + w * bf2f(row[j]);
      m_run = nm;
      row = nrow;
    }
  }

  const float inv = 1.f / (l_run > 0.f ? l_run : 1.f);

  // ---- fused residual + LayerNorm + ReLU (wave-wide reduce, no LDS)
  float xv[8];
  float sum = 0.f, sq = 0.f;
  {
    const float4 h0 = *(const float4*)(hF + (size_t)n * kD + d8);
    const float4 h1 = *(const float4*)(hF + (size_t)n * kD + d8 + 4);
    const float hv[8] = {h0.x, h0.y, h0.z, h0.w, h1.x, h1.y, h1.z, h1.w};
#pragma unroll
    for (int j = 0; j < 8; ++j) {
      xv[j] = hv[j] + acc[j] * inv + bias[d8 + j];
      sum += xv[j];
      sq  += xv[j] * xv[j];
    }
  }
#pragma unroll
  for (int off = 32; off > 0; off >>= 1) {
    sum += __shfl_xor(sum, off);
    sq  += __shfl_xor(sq, off);
  }
  const float mean = sum * (1.f / kD);
  const float var  = sq * (1.f / kD) - mean * mean;
  const float rs = rsqrtf(var + kLnEps);
  float y[8];
  u16x8 pk;
#pragma unroll
  for (int j = 0; j < 8; ++j) {
    y[j] = fmaxf((xv[j] - mean) * rs * lng[d8 + j] + lnb[d8 + j], 0.f);
    pk[j] = f2bf(y[j]);
  }
  float4 o0, o1;
  o0.x = y[0]; o0.y = y[1]; o0.z = y[2]; o0.w = y[3];
  o1.x = y[4]; o1.y = y[5]; o1.z = y[6]; o1.w = y[7];
  *(float4*)(hF + (size_t)n * kD + d8)     = o0;
  *(float4*)(hF + (size_t)n * kD + d8 + 4) = o1;
  *(u16x8*)(hb + (size_t)n * kD + d8) = pk;
}

// ---------------------------------------------------------------------------
// Batched transpose: dst[n][k] = bf16(src[k][n]); all jobs have N=512 cols.
// Grid (32,16,nJobs); jobs with K=512 use only bx<16.
// ---------------------------------------------------------------------------
struct TxJobs {
  const float* src[10];
  u16* dst[10];
  int K[10];
};

__global__ __launch_bounds__(256) void transpose_all_kernel(TxJobs jobs) {
  const int z = blockIdx.z;
  const int K = jobs.K[z];
  const int k0 = blockIdx.x * 32;
  if (k0 >= K) return;
  const int n0 = blockIdx.y * 32;
  const float* W = jobs.src[z];
  u16* WT = jobs.dst[z];
  __shared__ float t[32][33];
  const int lx = threadIdx.x & 31, ly = threadIdx.x >> 5;  // 32 x 8
#pragma unroll
  for (int r = 0; r < 32; r += 8)
    t[ly + r][lx] = W[(size_t)(k0 + ly + r) * 512 + n0 + lx];
  __syncthreads();
#pragma unroll
  for (int r = 0; r < 32; r += 8)
    WT[(size_t)(n0 + ly + r) * K + k0 + lx] = f2bf(t[lx][ly + r]);
}

__global__ void convert_bf16_kernel(const float* __restrict__ in,
                                    u16* __restrict__ out, int n4) {
  const int i = blockIdx.x * 256 + threadIdx.x;
  if (i >= n4) return;
  const float4 v = reinterpret_cast<const float4*>(in)[i];
  u16 o[4] = {f2bf(v.x), f2bf(v.y), f2bf(v.z), f2bf(v.w)};
  *reinterpret_cast<ulonglong1*>(out + (size_t)i * 4) =
      *reinterpret_cast<ulonglong1*>(o);
}

// catB[k][j] = j<512 ? bl[k][j] : br[k][j-512]
__global__ void catbias_kernel(const float* __restrict__ bl,
                               const float* __restrict__ br,
                               float* __restrict__ catB) {
  const int i = blockIdx.x * 256 + threadIdx.x;  // 3*1024
  if (i >= 3 * 1024) return;
  const int k = i >> 10, j = i & 1023;
  catB[i] = (j < 512) ? bl[k * 512 + j] : br[k * 512 + j - 512];
}

// ------------------------- CSR build helpers -------------------------------
__global__ void fill_i32(int* p, int v, int n) {
  const int i = blockIdx.x * 256 + threadIdx.x;
  if (i < n) p[i] = v;
}
__global__ void copy_i32(const int* a, int* b, int n) {
  const int i = blockIdx.x * 256 + threadIdx.x;
  if (i < n) b[i] = a[i];
}
__global__ void count_kernel(const int* __restrict__ dst, int* __restrict__ counts) {
  const int e = blockIdx.x * 256 + threadIdx.x;
  if (e < kE) atomicAdd(&counts[dst[e]], 1);
}
__global__ __launch_bounds__(1024) void scan_kernel(const int* __restrict__ counts,
                                                    int* __restrict__ offs, int n) {
  __shared__ int buf[1024];
  __shared__ int carry;
  const int tid = threadIdx.x;
  if (tid == 0) carry = 0;
  __syncthreads();
  for (int base = 0; base < n; base += 1024) {
    const int v = (base + tid < n) ? counts[base + tid] : 0;
    buf[tid] = v;
    __syncthreads();
    for (int off = 1; off < 1024; off <<= 1) {
      const int t = (tid >= off) ? buf[tid - off] : 0;
      __syncthreads();
      buf[tid] += t;
      __syncthreads();
    }
    if (base + tid < n) offs[base + tid] = carry + buf[tid] - v;
    __syncthreads();
    if (tid == 0) carry += buf[1023];
    __syncthreads();
  }
  if (tid == 0) offs[n] = carry;
}
__global__ void scatter_kernel(const int* __restrict__ dst, int* __restrict__ pos,
                               int* __restrict__ sorted) {
  const int e = blockIdx.x * 256 + threadIdx.x;
  if (e >= kE) return;
  const int p = atomicAdd(&pos[dst[e]], 1);
  sorted[p] = e;
}

}  // namespace

extern "C" void kernel_launch(void* const* d_in, const int* in_sizes, int n_in,
                              void* d_out, int out_size, void* d_ws, size_t ws_size,
                              hipStream_t stream) {
  const float* x         = (const float*)d_in[0];
  const float* edge_attr = (const float*)d_in[1];
  const float* emb_inv_W = (const float*)d_in[2];
  const float* emb_inv_b = (const float*)d_in[3];
  const float* emb_org_W = (const float*)d_in[4];
  const float* emb_org_b = (const float*)d_in[5];
  const float* gat_Wl    = (const float*)d_in[6];
  const float* gat_bl    = (const float*)d_in[7];
  const float* gat_Wr    = (const float*)d_in[8];
  const float* gat_br    = (const float*)d_in[9];
  const float* gat_We    = (const float*)d_in[10];
  const float* gat_att   = (const float*)d_in[11];
  const float* gat_bias  = (const float*)d_in[12];
  const float* ln_g      = (const float*)d_in[13];
  const float* ln_b      = (const float*)d_in[14];
  const float* lin0_W    = (const float*)d_in[15];
  const float* lin0_b    = (const float*)d_in[16];
  const float* lin1_W    = (const float*)d_in[17];
  const float* lin1_b    = (const float*)d_in[18];
  const int*   edge_idx  = (const int*)d_in[19];
  const int* src = edge_idx;
  const int* dst = edge_idx + kE;
  float* out = (float*)d_out;

  // ---- workspace layout (~86 MB) ----
  float* hF   = (float*)d_ws;          // [N,D] residual stream (f32)
  float* catB = hF + kND;              // [3,1024] concat gat biases
  u16* xb   = (u16*)(catB + 3072);     // [N,D] bf16(x)
  u16* hb0  = xb + kND;                // [N,D] bf16 initial embedding
  u16* hb   = hb0 + kND;               // [N,D] bf16 running h
  u16* xlB  = hb + kND;                // [N,D]
  u16* xrB  = xlB + kND;               // [N,D]
  u16* y0b  = xrB + kND;               // [4000,512]
  u16* y1b  = y0b + kNinv * kD;        // [3000,512]
  u16* embInvT = y1b + kNunk * kD;     // [512,512]
  u16* embOrgT = embInvT + 262144;
  u16* WlrT    = embOrgT + 262144;     // 3 x [1024,512] (WlT rows 0-511, WrT 512-1023)
  u16* lin0T   = WlrT + 3 * 524288;    // [512,1024]
  u16* lin1T   = lin0T + 524288;
  int* counts  = (int*)(lin1T + 524288);
  int* offs    = counts + kN;
  int* pos     = offs + kN + 1;
  int* sorted  = pos + kN;

  const dim3 blk(256);
  auto cdiv = [](int a, int b) { return (a + b - 1) / b; };

  // ---- 0. setup: batched weight transpose + x convert + concat bias
  {
    TxJobs j;
    j.src[0] = emb_inv_W;  j.dst[0] = embInvT;  j.K[0] = 512;
    j.src[1] = emb_org_W;  j.dst[1] = embOrgT;  j.K[1] = 512;
    for (int k = 0; k < 3; ++k) {
      j.src[2 + k] = gat_Wl + (size_t)k * kD * kD;
      j.dst[2 + k] = WlrT + (size_t)k * 524288;            // rows 0..511
      j.K[2 + k] = 512;
      j.src[5 + k] = gat_Wr + (size_t)k * kD * kD;
      j.dst[5 + k] = WlrT + (size_t)k * 524288 + 262144;   // rows 512..1023
      j.K[5 + k] = 512;
    }
    j.src[8] = lin0_W; j.dst[8] = lin0T; j.K[8] = 1024;
    j.src[9] = lin1_W; j.dst[9] = lin1T; j.K[9] = 1024;
    transpose_all_kernel<<<dim3(32, 16, 10), blk, 0, stream>>>(j);
  }
  convert_bf16_kernel<<<dim3(cdiv(kND / 4, 256)), blk, 0, stream>>>(x, xb, kND / 4);
  catbias_kernel<<<dim3(12), blk, 0, stream>>>(gat_bl, gat_br, catB);

  // ---- 1. embeddings -> hF (f32) + hb0 (bf16)
  gemm_bf16<true, true><<<dim3(cdiv(kNinv, 128), 4), blk, 0, stream>>>(
      xb, nullptr, embInvT, emb_inv_b, hF, hb0, nullptr, 0, kNinv, kD, kD, kD);
  gemm_bf16<true, true><<<dim3(cdiv(kN - kNinv, 128), 4), blk, 0, stream>>>(
      xb + (size_t)kNinv * kD, nullptr, embOrgT, emb_org_b,
      hF + (size_t)kNinv * kD, hb0 + (size_t)kNinv * kD, nullptr, 0,
      kN - kNinv, kD, kD, kD);

  // ---- 2. CSR over dst (reused by all 3 layers)
  fill_i32<<<dim3(cdiv(kN, 256)), blk, 0, stream>>>(counts, 0, kN);
  count_kernel<<<dim3(cdiv(kE, 256)), blk, 0, stream>>>(dst, counts);
  scan_kernel<<<dim3(1), dim3(1024), 0, stream>>>(counts, offs, kN);
  copy_i32<<<dim3(cdiv(kN, 256)), blk, 0, stream>>>(offs, pos, kN);
  scatter_kernel<<<dim3(cdiv(kE, 256)), blk, 0, stream>>>(dst, pos, sorted);

  // ---- 3. GAT layers: 1 fused lr-GEMM + 1 fused attention kernel each
  for (int k = 0; k < 3; ++k) {
    const u16* hIn = (k == 0) ? hb0 : hb;
    gemm_bf16<false, true><<<dim3(cdiv(kN, 128), 8), blk, 0, stream>>>(
        hIn, nullptr, WlrT + (size_t)k * 524288, catB + k * 1024,
        nullptr, xlB, xrB, 512, kN, 1024, kD, kD);
    gat_fused_kernel<<<dim3(cdiv(kN, 4)), blk, 0, stream>>>(
        xlB, xrB, edge_attr, src, offs, sorted,
        gat_We + (size_t)k * 2 * kD, gat_att + (size_t)k * kD,
        gat_bias + (size_t)k * kD, ln_g + (size_t)k * kD,
        ln_b + (size_t)k * kD, hF, hb);
  }

  // ---- 4. heads via A-split ([hb0 | hb] along K): y0, y1 (bf16)
  gemm_bf16<false, true><<<dim3(cdiv(kNinv, 128), 4), blk, 0, stream>>>(
      hb0, hb, lin0T, lin0_b, nullptr, y0b, nullptr, 0, kNinv, kD, 2 * kD, kD);
  const size_t off = (size_t)(kN - kNunk) * kD;
  gemm_bf16<false, true><<<dim3(cdiv(kNunk, 128), 4), blk, 0, stream>>>(
      hb0 + off, hb + off, lin1T, lin1_b, nullptr, y1b, nullptr, 0,
      kNunk, kD, 2 * kD, kD);

  // ---- 5. out = y0 @ y1^T  [4000,3000]
  gemm_bf16<true, false><<<dim3(cdiv(kNinv, 128), cdiv(kNunk, 128)), blk, 0, stream>>>(
      y0b, nullptr, y1b, nullptr, out, nullptr, nullptr, 0,
      kNinv, kNunk, kD, kNunk);
}

// Round 6
// 430.147 us; speedup vs baseline: 3.3755x; 1.0225x over previous
//
#include <hip/hip_runtime.h>
#include <cstddef>
#include <cstdint>

namespace {

using u16 = unsigned short;
typedef __attribute__((ext_vector_type(8))) unsigned short u16x8;
typedef __attribute__((ext_vector_type(8))) short bf16x8;
typedef __attribute__((ext_vector_type(4))) float f32x4;

constexpr int kN    = 10000;   // nodes
constexpr int kE    = 160000;  // edges
constexpr int kD    = 512;     // feature dim
constexpr int kNinv = 4000;
constexpr int kNunk = 3000;
constexpr int kND   = kN * kD;
constexpr float kNegSlope = 0.2f;
constexpr float kLnEps    = 1e-5f;

__device__ __forceinline__ float bf2f(u16 u) {
  return __uint_as_float((unsigned)u << 16);
}
__device__ __forceinline__ u16 f2bf(float f) {
  unsigned u = __float_as_uint(f);
  return (u16)((u + 0x7FFFu + ((u >> 16) & 1u)) >> 16);  // RNE
}

__device__ __forceinline__ void gload_lds16(const void* g, void* l) {
  __builtin_amdgcn_global_load_lds(
      (const __attribute__((address_space(1))) void*)(unsigned long long)(uintptr_t)g,
      (__attribute__((address_space(3))) void*)(unsigned)(uintptr_t)l,
      16, 0, 0);
}

// ---------------------------------------------------------------------------
// bf16 MFMA GEMM: C[M,N] = A[M,K](bf16) * BT[N,K]^T(bf16) (+ bias)
//   A = [A1 | A2] split along K at 512 when A2 != nullptr (row stride 512 each);
//   else A1 row stride K.
//   Cb2/nsplit: bf16 cols >= nsplit go to Cb2 (col-nsplit), both ldc wide.
// 128x128 tile, BK=64, 256 thr = 4 waves (2x2), 16x16x32 MFMA.
// global_load_lds(16B), XOR swizzle (both-sides: pre-swizzled source + swizzled
// ds_read) -> 2-way conflicts only (free).
// ---------------------------------------------------------------------------
template <bool WRITE_F32, bool WRITE_BF16>
__global__ __launch_bounds__(256) void gemm_bf16(
    const u16* __restrict__ A1, const u16* __restrict__ A2,
    const u16* __restrict__ BT, const float* __restrict__ bias,
    float* __restrict__ Cf, u16* __restrict__ Cb, u16* __restrict__ Cb2,
    int nsplit, int M, int N, int K, int ldc) {
  __shared__ u16 As[128 * 64];  // 16 KB
  __shared__ u16 Bs[128 * 64];  // 16 KB
  const int tid  = threadIdx.x;
  const int lane = tid & 63;
  const int wid  = tid >> 6;
  const int bm = blockIdx.x * 128;
  const int bn = blockIdx.y * 128;
  const int wr = (wid >> 1) * 64;
  const int wc = (wid & 1) * 64;

  f32x4 acc[4][4];
#pragma unroll
  for (int m = 0; m < 4; ++m)
#pragma unroll
    for (int n = 0; n < 4; ++n) acc[m][n] = (f32x4){0.f, 0.f, 0.f, 0.f};

  const int srow = lane >> 3;  // 0..7
  const int slot = lane & 7;   // 16B slot in 128B row
  const size_t astride = (A2 != nullptr) ? 512 : (size_t)K;

  for (int k0 = 0; k0 < K; k0 += 64) {
    const u16* Ap = A1;
    int kof = k0;
    if (A2 != nullptr && k0 >= 512) { Ap = A2; kof = k0 - 512; }
#pragma unroll
    for (int t = 0; t < 4; ++t) {
      const int inst = wid * 4 + t;
      const int row  = inst * 8 + srow;
      const int scol = ((slot ^ (row & 7)) << 4);
      const int ar   = min(bm + row, M - 1);
      gload_lds16((const char*)Ap + ((size_t)ar * astride + kof) * 2 + scol,
                  (char*)As + inst * 1024);
    }
#pragma unroll
    for (int t = 0; t < 4; ++t) {
      const int inst = wid * 4 + t;
      const int row  = inst * 8 + srow;
      const int scol = ((slot ^ (row & 7)) << 4);
      const int bc   = min(bn + row, N - 1);
      gload_lds16((const char*)BT + ((size_t)bc * K + k0) * 2 + scol,
                  (char*)Bs + inst * 1024);
    }
    asm volatile("s_waitcnt vmcnt(0)" ::: "memory");
    __syncthreads();

#pragma unroll
    for (int kk = 0; kk < 2; ++kk) {
      bf16x8 af[4], bfr[4];
#pragma unroll
      for (int m = 0; m < 4; ++m) {
        const int r = wr + m * 16 + (lane & 15);
        const int s = kk * 4 + (lane >> 4);
        af[m] = *(const bf16x8*)((const char*)As + r * 128 + ((s ^ (r & 7)) << 4));
      }
#pragma unroll
      for (int n = 0; n < 4; ++n) {
        const int c = wc + n * 16 + (lane & 15);
        const int s = kk * 4 + (lane >> 4);
        bfr[n] = *(const bf16x8*)((const char*)Bs + c * 128 + ((s ^ (c & 7)) << 4));
      }
#pragma unroll
      for (int m = 0; m < 4; ++m)
#pragma unroll
        for (int n = 0; n < 4; ++n)
          acc[m][n] = __builtin_amdgcn_mfma_f32_16x16x32_bf16(af[m], bfr[n],
                                                              acc[m][n], 0, 0, 0);
    }
    __syncthreads();
  }

  // C/D layout: col = lane&15, row = (lane>>4)*4 + j  [m89/m91]
#pragma unroll
  for (int m = 0; m < 4; ++m) {
    const int row0 = bm + wr + m * 16 + ((lane >> 4) << 2);
#pragma unroll
    for (int n = 0; n < 4; ++n) {
      const int col = bn + wc + n * 16 + (lane & 15);
      if (col < N) {
        const float bv = (bias != nullptr) ? bias[col] : 0.f;
#pragma unroll
        for (int j = 0; j < 4; ++j) {
          const int r = row0 + j;
          if (r < M) {
            const float v = acc[m][n][j] + bv;
            if (WRITE_F32) Cf[(size_t)r * ldc + col] = v;
            if (WRITE_BF16) {
              u16* dstp = Cb;
              int c = col;
              if (Cb2 != nullptr && col >= nsplit) { dstp = Cb2; c = col - nsplit; }
              dstp[(size_t)r * ldc + c] = f2bf(v);
            }
          }
        }
      }
    }
  }
}

// ---------------------------------------------------------------------------
// Fused per-node GATv2 attention + residual + LayerNorm + ReLU.
// ONE WAVE PER NODE, 4 EDGES PER ITERATION: zero LDS, zero barriers.
// 64 lanes x 8 dims = 512. Per 4-edge group: 4 row loads in flight, 4
// interleaved dot/shuffle-reduce chains (pipelined), ONE batched online-
// softmax rescale. leaky_relu via branch-free 0.6m+0.4|m| with pre-scaled
// att vectors (|m| is a free VALU input modifier). All group-tail guards
// are wave-uniform (cnt is per-node) -> no divergence.
// ---------------------------------------------------------------------------
__global__ __launch_bounds__(256) void gat_fused_kernel(
    const u16* __restrict__ xl, const u16* __restrict__ xr,
    const float* __restrict__ ea, const int* __restrict__ src,
    const int* __restrict__ offs, const int* __restrict__ sorted,
    const float* __restrict__ We, const float* __restrict__ att,
    const float* __restrict__ bias, const float* __restrict__ lng,
    const float* __restrict__ lnb, float* __restrict__ hF,
    u16* __restrict__ hb) {
  const int tid = threadIdx.x, wid = tid >> 6, lane = tid & 63;
  const int n = blockIdx.x * 4 + wid;
  if (n >= kN) return;
  const int d8 = lane * 8;

  // ---- per-node register state
  float r8[8], w0[8], w1[8], a06[8], a04[8];
  {
    const u16x8 rv = *(const u16x8*)(xr + (size_t)n * kD + d8);
#pragma unroll
    for (int i = 0; i < 8; ++i) {
      r8[i] = bf2f(rv[i]);
      w0[i] = We[d8 + i];
      w1[i] = We[kD + d8 + i];
      const float a = att[d8 + i];
      a06[i] = 0.6f * a;      // lrelu(m) = 0.6m + 0.4|m| for slope 0.2
      a04[i] = 0.4f * a;
    }
  }

  float acc[8];
#pragma unroll
  for (int j = 0; j < 8; ++j) acc[j] = 0.f;
  float m_run = -INFINITY, l_run = 0.f;

  const int beg = offs[n], end = offs[n + 1];
  for (int base = beg; base < end; base += 64) {
    const int cnt = min(64, end - base);
    // lane i holds edge i's (src, ea) — one parallel metadata round
    const int e  = sorted[base + ((lane < cnt) ? lane : 0)];
    const int sv = src[e];
    const float2 e2 = *(const float2*)(ea + (size_t)e * 2);

    for (int i = 0; i < cnt; i += 4) {
      const int k = cnt - i;  // >=1; all guards below are wave-uniform
      // ---- issue up to 4 row loads back-to-back (4KB in flight)
      u16x8 r0, r1, r2, r3;
      r0 = *(const u16x8*)(xl + (size_t)__shfl(sv, i) * kD + d8);
      if (k > 1) r1 = *(const u16x8*)(xl + (size_t)__shfl(sv, i + 1) * kD + d8);
      if (k > 2) r2 = *(const u16x8*)(xl + (size_t)__shfl(sv, i + 2) * kD + d8);
      if (k > 3) r3 = *(const u16x8*)(xl + (size_t)__shfl(sv, i + 3) * kD + d8);
      // ---- 4 independent dots
      float s0 = 0.f, s1 = 0.f, s2 = 0.f, s3 = 0.f;
      {
        const float ex = __shfl(e2.x, i), ey = __shfl(e2.y, i);
#pragma unroll
        for (int j = 0; j < 8; ++j) {
          const float m = bf2f(r0[j]) + r8[j] + ex * w0[j] + ey * w1[j];
          s0 += a06[j] * m + a04[j] * fabsf(m);
        }
      }
      if (k > 1) {
        const float ex = __shfl(e2.x, i + 1), ey = __shfl(e2.y, i + 1);
#pragma unroll
        for (int j = 0; j < 8; ++j) {
          const float m = bf2f(r1[j]) + r8[j] + ex * w0[j] + ey * w1[j];
          s1 += a06[j] * m + a04[j] * fabsf(m);
        }
      }
      if (k > 2) {
        const float ex = __shfl(e2.x, i + 2), ey = __shfl(e2.y, i + 2);
#pragma unroll
        for (int j = 0; j < 8; ++j) {
          const float m = bf2f(r2[j]) + r8[j] + ex * w0[j] + ey * w1[j];
          s2 += a06[j] * m + a04[j] * fabsf(m);
        }
      }
      if (k > 3) {
        const float ex = __shfl(e2.x, i + 3), ey = __shfl(e2.y, i + 3);
#pragma unroll
        for (int j = 0; j < 8; ++j) {
          const float m = bf2f(r3[j]) + r8[j] + ex * w0[j] + ey * w1[j];
          s3 += a06[j] * m + a04[j] * fabsf(m);
        }
      }
      // ---- interleaved shuffle reduces (independent chains pipeline)
#pragma unroll
      for (int off = 32; off > 0; off >>= 1) {
        s0 += __shfl_xor(s0, off);
        if (k > 1) s1 += __shfl_xor(s1, off);
        if (k > 2) s2 += __shfl_xor(s2, off);
        if (k > 3) s3 += __shfl_xor(s3, off);
      }
      // ---- ONE batched online-softmax update for the group
      float gm = s0;
      if (k > 1) gm = fmaxf(gm, s1);
      if (k > 2) gm = fmaxf(gm, s2);
      if (k > 3) gm = fmaxf(gm, s3);
      const float nm = fmaxf(m_run, gm);
      const float sc = __expf(m_run - nm);  // first group: exp(-inf)=0
      const float q0 = __expf(s0 - nm);
      float wsum = q0;
      float q1 = 0.f, q2 = 0.f, q3 = 0.f;
      if (k > 1) { q1 = __expf(s1 - nm); wsum += q1; }
      if (k > 2) { q2 = __expf(s2 - nm); wsum += q2; }
      if (k > 3) { q3 = __expf(s3 - nm); wsum += q3; }
      l_run = l_run * sc + wsum;
#pragma unroll
      for (int j = 0; j < 8; ++j) {
        float v = q0 * bf2f(r0[j]);
        if (k > 1) v += q1 * bf2f(r1[j]);
        if (k > 2) v += q2 * bf2f(r2[j]);
        if (k > 3) v += q3 * bf2f(r3[j]);
        acc[j] = acc[j] * sc + v;
      }
      m_run = nm;
    }
  }

  const float inv = 1.f / (l_run > 0.f ? l_run : 1.f);

  // ---- fused residual + LayerNorm + ReLU (wave-wide reduce, no LDS)
  float xv[8];
  float sum = 0.f, sq = 0.f;
  {
    const float4 h0 = *(const float4*)(hF + (size_t)n * kD + d8);
    const float4 h1 = *(const float4*)(hF + (size_t)n * kD + d8 + 4);
    const float hv[8] = {h0.x, h0.y, h0.z, h0.w, h1.x, h1.y, h1.z, h1.w};
#pragma unroll
    for (int j = 0; j < 8; ++j) {
      xv[j] = hv[j] + acc[j] * inv + bias[d8 + j];
      sum += xv[j];
      sq  += xv[j] * xv[j];
    }
  }
#pragma unroll
  for (int off = 32; off > 0; off >>= 1) {
    sum += __shfl_xor(sum, off);
    sq  += __shfl_xor(sq, off);
  }
  const float mean = sum * (1.f / kD);
  const float var  = sq * (1.f / kD) - mean * mean;
  const float rs = rsqrtf(var + kLnEps);
  float y[8];
  u16x8 pk;
#pragma unroll
  for (int j = 0; j < 8; ++j) {
    y[j] = fmaxf((xv[j] - mean) * rs * lng[d8 + j] + lnb[d8 + j], 0.f);
    pk[j] = f2bf(y[j]);
  }
  float4 o0, o1;
  o0.x = y[0]; o0.y = y[1]; o0.z = y[2]; o0.w = y[3];
  o1.x = y[4]; o1.y = y[5]; o1.z = y[6]; o1.w = y[7];
  *(float4*)(hF + (size_t)n * kD + d8)     = o0;
  *(float4*)(hF + (size_t)n * kD + d8 + 4) = o1;
  *(u16x8*)(hb + (size_t)n * kD + d8) = pk;
}

// ---------------------------------------------------------------------------
// Batched transpose: dst[n][k] = bf16(src[k][n]); all jobs have N=512 cols.
// Grid (32,16,nJobs); jobs with K=512 use only bx<16.
// ---------------------------------------------------------------------------
struct TxJobs {
  const float* src[10];
  u16* dst[10];
  int K[10];
};

__global__ __launch_bounds__(256) void transpose_all_kernel(TxJobs jobs) {
  const int z = blockIdx.z;
  const int K = jobs.K[z];
  const int k0 = blockIdx.x * 32;
  if (k0 >= K) return;
  const int n0 = blockIdx.y * 32;
  const float* W = jobs.src[z];
  u16* WT = jobs.dst[z];
  __shared__ float t[32][33];
  const int lx = threadIdx.x & 31, ly = threadIdx.x >> 5;  // 32 x 8
#pragma unroll
  for (int r = 0; r < 32; r += 8)
    t[ly + r][lx] = W[(size_t)(k0 + ly + r) * 512 + n0 + lx];
  __syncthreads();
#pragma unroll
  for (int r = 0; r < 32; r += 8)
    WT[(size_t)(n0 + ly + r) * K + k0 + lx] = f2bf(t[lx][ly + r]);
}

__global__ void convert_bf16_kernel(const float* __restrict__ in,
                                    u16* __restrict__ out, int n4) {
  const int i = blockIdx.x * 256 + threadIdx.x;
  if (i >= n4) return;
  const float4 v = reinterpret_cast<const float4*>(in)[i];
  u16 o[4] = {f2bf(v.x), f2bf(v.y), f2bf(v.z), f2bf(v.w)};
  *reinterpret_cast<ulonglong1*>(out + (size_t)i * 4) =
      *reinterpret_cast<ulonglong1*>(o);
}

// catB[k][j] = j<512 ? bl[k][j] : br[k][j-512]
__global__ void catbias_kernel(const float* __restrict__ bl,
                               const float* __restrict__ br,
                               float* __restrict__ catB) {
  const int i = blockIdx.x * 256 + threadIdx.x;  // 3*1024
  if (i >= 3 * 1024) return;
  const int k = i >> 10, j = i & 1023;
  catB[i] = (j < 512) ? bl[k * 512 + j] : br[k * 512 + j - 512];
}

// ------------------------- CSR build helpers -------------------------------
__global__ void fill_i32(int* p, int v, int n) {
  const int i = blockIdx.x * 256 + threadIdx.x;
  if (i < n) p[i] = v;
}
__global__ void copy_i32(const int* a, int* b, int n) {
  const int i = blockIdx.x * 256 + threadIdx.x;
  if (i < n) b[i] = a[i];
}
__global__ void count_kernel(const int* __restrict__ dst, int* __restrict__ counts) {
  const int e = blockIdx.x * 256 + threadIdx.x;
  if (e < kE) atomicAdd(&counts[dst[e]], 1);
}
__global__ __launch_bounds__(1024) void scan_kernel(const int* __restrict__ counts,
                                                    int* __restrict__ offs, int n) {
  __shared__ int buf[1024];
  __shared__ int carry;
  const int tid = threadIdx.x;
  if (tid == 0) carry = 0;
  __syncthreads();
  for (int base = 0; base < n; base += 1024) {
    const int v = (base + tid < n) ? counts[base + tid] : 0;
    buf[tid] = v;
    __syncthreads();
    for (int off = 1; off < 1024; off <<= 1) {
      const int t = (tid >= off) ? buf[tid - off] : 0;
      __syncthreads();
      buf[tid] += t;
      __syncthreads();
    }
    if (base + tid < n) offs[base + tid] = carry + buf[tid] - v;
    __syncthreads();
    if (tid == 0) carry += buf[1023];
    __syncthreads();
  }
  if (tid == 0) offs[n] = carry;
}
__global__ void scatter_kernel(const int* __restrict__ dst, int* __restrict__ pos,
                               int* __restrict__ sorted) {
  const int e = blockIdx.x * 256 + threadIdx.x;
  if (e >= kE) return;
  const int p = atomicAdd(&pos[dst[e]], 1);
  sorted[p] = e;
}

}  // namespace

extern "C" void kernel_launch(void* const* d_in, const int* in_sizes, int n_in,
                              void* d_out, int out_size, void* d_ws, size_t ws_size,
                              hipStream_t stream) {
  const float* x         = (const float*)d_in[0];
  const float* edge_attr = (const float*)d_in[1];
  const float* emb_inv_W = (const float*)d_in[2];
  const float* emb_inv_b = (const float*)d_in[3];
  const float* emb_org_W = (const float*)d_in[4];
  const float* emb_org_b = (const float*)d_in[5];
  const float* gat_Wl    = (const float*)d_in[6];
  const float* gat_bl    = (const float*)d_in[7];
  const float* gat_Wr    = (const float*)d_in[8];
  const float* gat_br    = (const float*)d_in[9];
  const float* gat_We    = (const float*)d_in[10];
  const float* gat_att   = (const float*)d_in[11];
  const float* gat_bias  = (const float*)d_in[12];
  const float* ln_g      = (const float*)d_in[13];
  const float* ln_b      = (const float*)d_in[14];
  const float* lin0_W    = (const float*)d_in[15];
  const float* lin0_b    = (const float*)d_in[16];
  const float* lin1_W    = (const float*)d_in[17];
  const float* lin1_b    = (const float*)d_in[18];
  const int*   edge_idx  = (const int*)d_in[19];
  const int* src = edge_idx;
  const int* dst = edge_idx + kE;
  float* out = (float*)d_out;

  // ---- workspace layout (~86 MB) ----
  float* hF   = (float*)d_ws;          // [N,D] residual stream (f32)
  float* catB = hF + kND;              // [3,1024] concat gat biases
  u16* xb   = (u16*)(catB + 3072);     // [N,D] bf16(x)
  u16* hb0  = xb + kND;                // [N,D] bf16 initial embedding
  u16* hb   = hb0 + kND;               // [N,D] bf16 running h
  u16* xlB  = hb + kND;                // [N,D]
  u16* xrB  = xlB + kND;               // [N,D]
  u16* y0b  = xrB + kND;               // [4000,512]
  u16* y1b  = y0b + kNinv * kD;        // [3000,512]
  u16* embInvT = y1b + kNunk * kD;     // [512,512]
  u16* embOrgT = embInvT + 262144;
  u16* WlrT    = embOrgT + 262144;     // 3 x [1024,512] (WlT rows 0-511, WrT 512-1023)
  u16* lin0T   = WlrT + 3 * 524288;    // [512,1024]
  u16* lin1T   = lin0T + 524288;
  int* counts  = (int*)(lin1T + 524288);
  int* offs    = counts + kN;
  int* pos     = offs + kN + 1;
  int* sorted  = pos + kN;

  const dim3 blk(256);
  auto cdiv = [](int a, int b) { return (a + b - 1) / b; };

  // ---- 0. setup: batched weight transpose + x convert + concat bias
  {
    TxJobs j;
    j.src[0] = emb_inv_W;  j.dst[0] = embInvT;  j.K[0] = 512;
    j.src[1] = emb_org_W;  j.dst[1] = embOrgT;  j.K[1] = 512;
    for (int k = 0; k < 3; ++k) {
      j.src[2 + k] = gat_Wl + (size_t)k * kD * kD;
      j.dst[2 + k] = WlrT + (size_t)k * 524288;            // rows 0..511
      j.K[2 + k] = 512;
      j.src[5 + k] = gat_Wr + (size_t)k * kD * kD;
      j.dst[5 + k] = WlrT + (size_t)k * 524288 + 262144;   // rows 512..1023
      j.K[5 + k] = 512;
    }
    j.src[8] = lin0_W; j.dst[8] = lin0T; j.K[8] = 1024;
    j.src[9] = lin1_W; j.dst[9] = lin1T; j.K[9] = 1024;
    transpose_all_kernel<<<dim3(32, 16, 10), blk, 0, stream>>>(j);
  }
  convert_bf16_kernel<<<dim3(cdiv(kND / 4, 256)), blk, 0, stream>>>(x, xb, kND / 4);
  catbias_kernel<<<dim3(12), blk, 0, stream>>>(gat_bl, gat_br, catB);

  // ---- 1. embeddings -> hF (f32) + hb0 (bf16)
  gemm_bf16<true, true><<<dim3(cdiv(kNinv, 128), 4), blk, 0, stream>>>(
      xb, nullptr, embInvT, emb_inv_b, hF, hb0, nullptr, 0, kNinv, kD, kD, kD);
  gemm_bf16<true, true><<<dim3(cdiv(kN - kNinv, 128), 4), blk, 0, stream>>>(
      xb + (size_t)kNinv * kD, nullptr, embOrgT, emb_org_b,
      hF + (size_t)kNinv * kD, hb0 + (size_t)kNinv * kD, nullptr, 0,
      kN - kNinv, kD, kD, kD);

  // ---- 2. CSR over dst (reused by all 3 layers)
  fill_i32<<<dim3(cdiv(kN, 256)), blk, 0, stream>>>(counts, 0, kN);
  count_kernel<<<dim3(cdiv(kE, 256)), blk, 0, stream>>>(dst, counts);
  scan_kernel<<<dim3(1), dim3(1024), 0, stream>>>(counts, offs, kN);
  copy_i32<<<dim3(cdiv(kN, 256)), blk, 0, stream>>>(offs, pos, kN);
  scatter_kernel<<<dim3(cdiv(kE, 256)), blk, 0, stream>>>(dst, pos, sorted);

  // ---- 3. GAT layers: 1 fused lr-GEMM + 1 fused attention kernel each
  for (int k = 0; k < 3; ++k) {
    const u16* hIn = (k == 0) ? hb0 : hb;
    gemm_bf16<false, true><<<dim3(cdiv(kN, 128), 8), blk, 0, stream>>>(
        hIn, nullptr, WlrT + (size_t)k * 524288, catB + k * 1024,
        nullptr, xlB, xrB, 512, kN, 1024, kD, kD);
    gat_fused_kernel<<<dim3(cdiv(kN, 4)), blk, 0, stream>>>(
        xlB, xrB, edge_attr, src, offs, sorted,
        gat_We + (size_t)k * 2 * kD, gat_att + (size_t)k * kD,
        gat_bias + (size_t)k * kD, ln_g + (size_t)k * kD,
        ln_b + (size_t)k * kD, hF, hb);
  }

  // ---- 4. heads via A-split ([hb0 | hb] along K): y0, y1 (bf16)
  gemm_bf16<false, true><<<dim3(cdiv(kNinv, 128), 4), blk, 0, stream>>>(
      hb0, hb, lin0T, lin0_b, nullptr, y0b, nullptr, 0, kNinv, kD, 2 * kD, kD);
  const size_t off = (size_t)(kN - kNunk) * kD;
  gemm_bf16<false, true><<<dim3(cdiv(kNunk, 128), 4), blk, 0, stream>>>(
      hb0 + off, hb + off, lin1T, lin1_b, nullptr, y1b, nullptr, 0,
      kNunk, kD, 2 * kD, kD);

  // ---- 5. out = y0 @ y1^T  [4000,3000]
  gemm_bf16<true, false><<<dim3(cdiv(kNinv, 128), cdiv(kNunk, 128)), blk, 0, stream>>>(
      y0b, nullptr, y1b, nullptr, out, nullptr, nullptr, 0,
      kNinv, kNunk, kD, kNunk);
}